// Round 17
// baseline (195.021 us; speedup 1.0000x reference)
//
#include <hip/hip_runtime.h>
#include <hip/hip_bf16.h>
#include <stdint.h>

// ---------- types ----------
typedef __attribute__((ext_vector_type(8))) short short8;      // 8 bf16 (MFMA A/B frag)
typedef __attribute__((ext_vector_type(4))) float floatx4;     // 16x16 C/D frag
typedef __attribute__((ext_vector_type(16))) float floatx16;   // 32x32 C/D frag
typedef __attribute__((ext_vector_type(4))) uint16_t ushort4v;

#define MFMA16(a, b, c) __builtin_amdgcn_mfma_f32_16x16x32_bf16((a), (b), (c), 0, 0, 0)
#define MFMA32(a, b, c) __builtin_amdgcn_mfma_f32_32x32x16_bf16((a), (b), (c), 0, 0, 0)

// async global->LDS, 16B per lane; LDS dest is wave-uniform base + lane*16
#define GLOAD_LDS16(g, l)                                                          \
  __builtin_amdgcn_global_load_lds(                                                \
      (const __attribute__((address_space(1))) uint32_t*)(g),                      \
      (__attribute__((address_space(3))) uint32_t*)(l), 16, 0, 0)

// packed f32x2 -> bf16x2
#define CVTPK(lo_, hi_, out_) \
  asm("v_cvt_pk_bf16_f32 %0, %1, %2" : "=v"(out_) : "v"(lo_), "v"(hi_))
// exchange a's high 32 lanes with b's low 32 lanes
#define SWAP32(a_, b_) \
  asm("v_permlane32_swap_b32 %0, %1" : "+v"(a_), "+v"(b_))

#define WAITVM(N)                                          \
  {                                                        \
    asm volatile("s_waitcnt vmcnt(" #N ")" ::: "memory");  \
    __builtin_amdgcn_sched_barrier(0);                     \
  }
#define SBAR                                               \
  {                                                        \
    __builtin_amdgcn_s_barrier();                          \
    __builtin_amdgcn_sched_barrier(0);                     \
  }

// fp32 -> bf16 round-to-nearest-even
__device__ __forceinline__ uint16_t f2bf(float x) {
  union { float f; uint32_t u; } c; c.f = x;
  return (uint16_t)((c.u + 0x7FFFu + ((c.u >> 16) & 1u)) >> 16);
}

// ---------- fp32 -> bf16 convert, all 7 tensors in one launch (z = 0..6) ----------
__global__ void cvt7_k(const float* __restrict__ q, const float* __restrict__ k,
                       const float* __restrict__ v, const float* __restrict__ w0,
                       const float* __restrict__ w1, const float* __restrict__ w2,
                       const float* __restrict__ w3, uint16_t* __restrict__ dstBig,
                       uint16_t* __restrict__ dstW) {
  const int z = blockIdx.z;
  const float* src;
  uint16_t* d;
  int n4;
  if (z < 3) {
    src = z == 0 ? q : (z == 1 ? k : v);
    d = dstBig + (size_t)z * 8388608;   // 16MB stride
    n4 = 2097152;
  } else {
    const int i = z - 3;
    src = i == 0 ? w0 : (i == 1 ? w1 : (i == 2 ? w2 : w3));
    d = dstW + (size_t)i * 1048576;     // 2MB stride
    n4 = 262144;
  }
  int stride = gridDim.x * blockDim.x;
  for (int i = blockIdx.x * blockDim.x + threadIdx.x; i < n4; i += stride) {
    float4 vv = ((const float4*)src)[i];
    ushort4v o;
    o.x = f2bf(vv.x); o.y = f2bf(vv.y); o.z = f2bf(vv.z); o.w = f2bf(vv.w);
    ((ushort4v*)d)[i] = o;
  }
}

// ======== GEMM A: 256x256 tile, per-wave 128x64, BK=64, 2-buf counted pipeline ====
// MFMA-bound geometry: per wave per K-tile 24 ds_read_b128 (288cyc) < 64 MFMA (320cyc).
// Schedule: compute(cur) -> SBAR -> stage kt+2 into cur (8 loads) -> vmcnt(8)
// (waits kt+1 only; kt+2 stays in flight) -> SBAR.
// LDS unit (R14-proven): 128 source rows x 64 k = 16KB; [64 r][16 slots x 16B],
// slot q of row r holds q0=q^(r&15): source row 64*(q0>>3)+r, kchunk q0&7.
// A = 2 units (rows 0-127,128-255); B = 2 units (cols 0-127,128-255). 32KB each/buf.
// MODE: 1 = bf16 out, 2 = bf16 V-transposed out.
template <int MODE>
__device__ __forceinline__ void gemm256sq_body(uint16_t* __restrict__ As,  // LDS 2*16384
                                               uint16_t* __restrict__ Bs,  // LDS 2*16384
                                               const uint16_t* __restrict__ A,
                                               const uint16_t* __restrict__ W,
                                               const float* __restrict__ bias,
                                               void* __restrict__ Cout, float scale,
                                               int brow, int bcol) {
  constexpr int N = 1024, K = 1024;
  const int t = threadIdx.x;
  const int l = t & 63, w = t >> 6;       // 8 waves
  const int l16 = l & 15, lhi = (l >> 4) & 3;
  const int wm = w >> 2, wn = w & 3;      // 2 M-waves x 4 N-waves; per-wave C 128x64

  // staging sources (advance +64 per K-tile); 4 issues each for A and B
  const uint16_t* pA[4];
  const uint16_t* pB[4];
#pragma unroll
  for (int i = 0; i < 4; ++i) {
    int cw = (i * 512 + t) & 1023;        // within-unit chunk
    int r = cw >> 4, q = cw & 15;
    int q0 = q ^ (r & 15);
    int srow = (i >> 1) * 128 + 64 * (q0 >> 3) + r;
    pA[i] = A + (size_t)(brow + srow) * K + (q0 & 7) * 8;
    pB[i] = W + (size_t)(bcol + srow) * K + (q0 & 7) * 8;
  }

#define G2_STAGE(BUF)                                                     \
  {                                                                       \
    _Pragma("unroll") for (int i = 0; i < 4; ++i) {                       \
      GLOAD_LDS16(pA[i], As + (BUF) * 16384 + i * 4096 + w * 512);        \
      GLOAD_LDS16(pB[i], Bs + (BUF) * 16384 + i * 4096 + w * 512);        \
      pA[i] += 64;                                                        \
      pB[i] += 64;                                                        \
    }                                                                     \
  }

  floatx4 acc[8][4] = {};

  // A-frag (m=0..7, ks): byte = wm*16384 + ((m&3)*16+l16)*256
  //                             + ((((m>>2)*8) + ks*4 + lhi) ^ l16)*16
  // B-frag (n=0..3, ks): byte = (wn>>1)*16384 + (n*16+l16)*256
  //                             + ((((wn&1)*8) + ks*4 + lhi) ^ l16)*16
#define G2_COMPUTE(BUF)                                                              \
  {                                                                                  \
    _Pragma("unroll") for (int ks = 0; ks < 2; ++ks) {                               \
      short8 a[8], b[4];                                                             \
      _Pragma("unroll") for (int m = 0; m < 8; ++m)                                  \
        a[m] = *(const short8*)((const char*)As + (BUF) * 32768 + wm * 16384 +       \
            ((m & 3) * 16 + l16) * 256 + ((((m >> 2) * 8 + ks * 4 + lhi) ^ l16) << 4)); \
      _Pragma("unroll") for (int n = 0; n < 4; ++n)                                  \
        b[n] = *(const short8*)((const char*)Bs + (BUF) * 32768 + (wn >> 1) * 16384 + \
            (n * 16 + l16) * 256 + ((((wn & 1) * 8 + ks * 4 + lhi) ^ l16) << 4));    \
      __builtin_amdgcn_s_setprio(1);                                                 \
      _Pragma("unroll") for (int m = 0; m < 8; ++m)                                  \
        _Pragma("unroll") for (int n = 0; n < 4; ++n)                                \
          acc[m][n] = MFMA16(a[m], b[n], acc[m][n]);                                 \
      __builtin_amdgcn_s_setprio(0);                                                 \
    }                                                                                \
  }

  // prologue: stage kt0 -> buf0, kt1 -> buf1; wait kt0 (8 of 16 oldest)
  G2_STAGE(0);
  G2_STAGE(1);
  WAITVM(8);
  SBAR;

  // kt = 0..13 (stage kt+2 = 2..15 into the buffer just read)
#pragma unroll 1
  for (int g = 0; g < 7; ++g) {
    G2_COMPUTE(0); SBAR; G2_STAGE(0); WAITVM(8); SBAR;
    G2_COMPUTE(1); SBAR; G2_STAGE(1); WAITVM(8); SBAR;
  }
  // kt=14 (buf0); then drain kt15's loads; kt=15 (buf1)
  G2_COMPUTE(0);
  WAITVM(0);
  SBAR;
  G2_COMPUTE(1);

  // ---- epilogue ----
#pragma unroll
  for (int n = 0; n < 4; ++n) {
    int col = bcol + wn * 64 + n * 16 + l16;
    float bv = bias[col];
    if (MODE == 2) {
      int h = col >> 6, d = col & 63;
#pragma unroll
      for (int m = 0; m < 8; ++m) {
        int row = brow + wm * 128 + m * 16 + lhi * 4;   // j=0 row
        int b_ = row >> 11, s = row & 2047;
        union { uint16_t u[4]; ushort4v v; } pk4;
#pragma unroll
        for (int j = 0; j < 4; ++j) pk4.u[j] = f2bf(acc[m][n][j] + bv);
        *(ushort4v*)((uint16_t*)Cout + (size_t)(b_ * 16 + h) * 131072 + (size_t)d * 2048 + s) = pk4.v;
      }
    } else {
#pragma unroll
      for (int m = 0; m < 8; ++m) {
#pragma unroll
        for (int j = 0; j < 4; ++j) {
          int row = brow + wm * 128 + m * 16 + lhi * 4 + j;
          ((uint16_t*)Cout)[(size_t)row * N + col] = f2bf((acc[m][n][j] + bv) * scale);
        }
      }
    }
  }
#undef G2_STAGE
#undef G2_COMPUTE
}

// fused Q/K/V projections: 384 blocks (4x, 32y, 3z), XCD-chunked; V pre-transposed.
__global__ __launch_bounds__(512, 1)
void gemm_qkv_k(const uint16_t* __restrict__ XQ, const uint16_t* __restrict__ XK,
                const uint16_t* __restrict__ XV, const uint16_t* __restrict__ WQ,
                const uint16_t* __restrict__ WK, const uint16_t* __restrict__ WV,
                const float* __restrict__ bq, const float* __restrict__ bk,
                const float* __restrict__ bv, uint16_t* __restrict__ QP,
                uint16_t* __restrict__ KP, uint16_t* __restrict__ VT, float qscale) {
  __shared__ uint16_t As[2 * 16384];   // 64KB
  __shared__ uint16_t Bs[2 * 16384];   // 64KB
  const int f = (blockIdx.z * 32 + blockIdx.y) * 4 + blockIdx.x;
  const int virt = (f & 7) * 48 + (f >> 3);     // 384 = 8*48, bijective
  const int vz = virt >> 7;                     // 128 tiles per projection
  const int rem = virt & 127;
  const int vy = rem >> 2, vx = rem & 3;

  if (vz == 0)      gemm256sq_body<1>(As, Bs, XQ, WQ, bq, QP, qscale, vy * 256, vx * 256);
  else if (vz == 1) gemm256sq_body<1>(As, Bs, XK, WK, bk, KP, 1.0f,  vy * 256, vx * 256);
  else              gemm256sq_body<2>(As, Bs, XV, WV, bv, VT, 1.0f,  vy * 256, vx * 256);
}

// ======== GEMM B (proven R14): 256x128 tile, BK=64, 3-buffer counted pipeline =====
__device__ __forceinline__ void gemm256_body_f32(uint16_t* __restrict__ As,   // 3*16384
                                                 uint16_t* __restrict__ Bs,   // 3*8192
                                                 const uint16_t* __restrict__ A,
                                                 const uint16_t* __restrict__ W,
                                                 const float* __restrict__ bias,
                                                 float* __restrict__ Cout,
                                                 int brow, int bcol) {
  constexpr int N = 1024, K = 1024;
  const int t = threadIdx.x;
  const int l = t & 63, w = t >> 6;
  const int l16 = l & 15, lhi = (l >> 4) & 3;
  const int wm = w >> 1, wn = w & 1;

  const uint16_t* pA[4];
  const uint16_t* pB[2];
#pragma unroll
  for (int i = 0; i < 4; ++i) {
    int cw = (i * 512 + t) & 1023;
    int r = cw >> 4, q = cw & 15;
    int q0 = q ^ (r & 15);
    pA[i] = A + (size_t)(brow + (i >> 1) * 128 + 64 * (q0 >> 3) + r) * K + (q0 & 7) * 8;
  }
#pragma unroll
  for (int i = 0; i < 2; ++i) {
    int c = i * 512 + t;
    int r = c >> 4, q = c & 15;
    int q0 = q ^ (r & 15);
    pB[i] = W + (size_t)(bcol + 64 * (q0 >> 3) + r) * K + (q0 & 7) * 8;
  }

#define G_STAGE(BUF)                                                      \
  {                                                                       \
    _Pragma("unroll") for (int i = 0; i < 4; ++i) {                       \
      GLOAD_LDS16(pA[i], As + (BUF) * 16384 + i * 4096 + w * 512);        \
      pA[i] += 64;                                                        \
    }                                                                     \
    _Pragma("unroll") for (int i = 0; i < 2; ++i) {                       \
      GLOAD_LDS16(pB[i], Bs + (BUF) * 8192 + i * 4096 + w * 512);         \
      pB[i] += 64;                                                        \
    }                                                                     \
  }

  floatx4 acc[4][4] = {};

#define G_COMPUTE(BUF)                                                               \
  {                                                                                  \
    short8 a[4][2], b[4][2];                                                         \
    _Pragma("unroll") for (int m = 0; m < 4; ++m)                                    \
      _Pragma("unroll") for (int ks = 0; ks < 2; ++ks)                               \
        a[m][ks] = *(const short8*)((const char*)(As + (BUF) * 16384) +              \
            (wm >> 1) * 16384 +                                                      \
            (m * 16 + l16) * 256 + ((((wm & 1) * 8 + ks * 4 + lhi) ^ l16) << 4));    \
    _Pragma("unroll") for (int n = 0; n < 4; ++n)                                    \
      _Pragma("unroll") for (int ks = 0; ks < 2; ++ks)                               \
        b[n][ks] = *(const short8*)((const char*)(Bs + (BUF) * 8192) +               \
            (n * 16 + l16) * 256 + (((wn * 8 + ks * 4 + lhi) ^ l16) << 4));          \
    __builtin_amdgcn_s_setprio(1);                                                   \
    _Pragma("unroll") for (int ks = 0; ks < 2; ++ks)                                 \
      _Pragma("unroll") for (int m = 0; m < 4; ++m)                                  \
        _Pragma("unroll") for (int n = 0; n < 4; ++n)                                \
          acc[m][n] = MFMA16(a[m][ks], b[n][ks], acc[m][n]);                         \
    __builtin_amdgcn_s_setprio(0);                                                   \
  }

#define G_STEP(RD, ST)   \
  {                      \
    G_STAGE(ST);         \
    G_COMPUTE(RD);       \
    WAITVM(6);           \
    SBAR;                \
  }

  G_STAGE(0);
  G_STAGE(1);
  WAITVM(6);
  SBAR;

#pragma unroll 1
  for (int g = 0; g < 4; ++g) {
    G_STEP(0, 2);
    G_STEP(1, 0);
    G_STEP(2, 1);
  }
  G_STEP(0, 2);
  G_STEP(1, 0);
  G_COMPUTE(2);
  WAITVM(0);
  SBAR;
  G_COMPUTE(0);

#pragma unroll
  for (int n = 0; n < 4; ++n) {
    int col = bcol + wn * 64 + n * 16 + l16;
    float bv = bias[col];
#pragma unroll
    for (int m = 0; m < 4; ++m) {
#pragma unroll
      for (int j = 0; j < 4; ++j) {
        int row = brow + wm * 64 + m * 16 + lhi * 4 + j;
        Cout[(size_t)row * N + col] = acc[m][n][j] + bv;
      }
    }
  }
#undef G_STAGE
#undef G_COMPUTE
#undef G_STEP
}

// output projection: 256 blocks (8x, 32y), XCD-chunked.
__global__ __launch_bounds__(512, 1)
void gemm_o_k(const uint16_t* __restrict__ A, const uint16_t* __restrict__ W,
              const float* __restrict__ bias, float* __restrict__ Cout) {
  __shared__ uint16_t As[3 * 16384];
  __shared__ uint16_t Bs[3 * 8192];
  const int f = blockIdx.y * 8 + blockIdx.x;
  const int virt = (f & 7) * 32 + (f >> 3);
  const int vy = virt >> 3, vx = virt & 7;
  gemm256_body_f32(As, Bs, A, W, bias, Cout, vy * 256, vx * 128);
}

// ---------- flash attention: quarter-pipelined (QK_next ∥ exp/pack_cur) ----------
__global__ __launch_bounds__(512, 2)
void attn_k(const uint16_t* __restrict__ Qp, const uint16_t* __restrict__ Kp,
            const uint16_t* __restrict__ Vt, uint16_t* __restrict__ AO) {
  __shared__ uint16_t Kl[2][64 * 128];   // 16KB per buffer
  __shared__ uint16_t Vl[2][64 * 128];   // 16KB per buffer

  const int t = threadIdx.x;
  const int l = t & 63, w = t >> 6;       // w = 0..7
  const int l32 = l & 31, hi = l >> 5;

  // XCD-chunked swizzle: 512 blocks, 64 per XCD -> 8 contiguous bh groups each.
  const int f = blockIdx.y * 8 + blockIdx.x;
  const int virt = (f & 7) * 64 + (f >> 3);
  const int vx = virt & 7;     // q-block (256 q each)
  const int vy = virt >> 3;    // bh

  const int q0 = vx * 256 + w * 32;
  const size_t base = (size_t)(vy >> 4) * 2048 * 1024 + (size_t)(vy & 15) * 64;
  const size_t vbg = (size_t)vy * 131072;  // (b*16+h)*64*2048

  union PAu { uint32_t u[4]; short8 s; };

  // staging: 1024 chunks per matrix per tile; 512 threads -> 2 issues each.
  const uint16_t* pK[2];
  const uint16_t* pV[2];
#pragma unroll
  for (int i = 0; i < 2; ++i) {
    int c = i * 512 + t;
    int r = c >> 4, qs = c & 15;
    int q0c = qs ^ (r & 15);
    pK[i] = Kp + base + (size_t)(64 * (q0c >> 3) + r) * 1024 + (q0c & 7) * 8;
    pV[i] = Vt + vbg + (size_t)r * 2048 + q0c * 8;
  }

#define STAGE_ALL(NB)                                                 \
  {                                                                   \
    _Pragma("unroll") for (int i = 0; i < 2; ++i) {                   \
      GLOAD_LDS16(pK[i], &Kl[NB][(size_t)(i * 512 + w * 64) * 8]);    \
      GLOAD_LDS16(pV[i], &Vl[NB][(size_t)(i * 512 + w * 64) * 8]);    \
      pK[i] += 131072;  /* +128 source rows */                        \
      pV[i] += 128;     /* +128 s columns  */                        \
    }                                                                 \
  }

  // Q B-frags: lane holds Q[q0 + l32][k = ks*16 + hi*8 + i]
  short8 qf[4];
#pragma unroll
  for (int ks = 0; ks < 4; ++ks)
    qf[ks] = *(const short8*)(Qp + base + (size_t)(q0 + l32) * 1024 + ks * 16 + hi * 8);

  floatx16 of0 = {}, of1 = {};   // O[q][d] C-frags
  float rs = 0.f;                // per-lane partial rowsum

  const int swzb = (l32 & 15);
  const int krow = l32 * 256;    // byte base of LDS row l32 (row +32 = +8192)

  STAGE_ALL(0);
  __syncthreads();

#define QK_Q(SF, CUR, H, RH)                                                          \
  {                                                                                   \
    _Pragma("unroll") for (int ks = 0; ks < 4; ++ks) {                                \
      int kbyte = krow + (RH) * 8192 + ((((H) * 8 + 2 * ks + hi) ^ swzb) << 4);       \
      short8 kf = *(const short8*)((char*)Kl[CUR] + kbyte);                           \
      SF = MFMA32(kf, qf[ks], SF);                                                    \
    }                                                                                 \
  }

#define EXPPACK(SF, P0, P1)                                                           \
  {                                                                                   \
    _Pragma("unroll") for (int r = 0; r < 16; ++r) {                                  \
      SF[r] = __builtin_amdgcn_exp2f(SF[r]);                                          \
      rs += SF[r];                                                                    \
    }                                                                                 \
    uint32_t a0, a1, b0, b1;                                                          \
    CVTPK(SF[0], SF[1], a0); CVTPK(SF[2], SF[3], a1);                                 \
    CVTPK(SF[4], SF[5], b0); CVTPK(SF[6], SF[7], b1);                                 \
    SWAP32(a0, b0); SWAP32(a1, b1);                                                   \
    P0.u[0] = a0; P0.u[1] = a1; P0.u[2] = b0; P0.u[3] = b1;                           \
    CVTPK(SF[8], SF[9], a0); CVTPK(SF[10], SF[11], a1);                               \
    CVTPK(SF[12], SF[13], b0); CVTPK(SF[14], SF[15], b1);                             \
    SWAP32(a0, b0); SWAP32(a1, b1);                                                   \
    P1.u[0] = a0; P1.u[1] = a1; P1.u[2] = b0; P1.u[3] = b1;                           \
  }

#define PV_Q(P0, P1, CUR, H, RH)                                                      \
  {                                                                                   \
    int vb0 = krow + ((((H) * 8 + 2 * (2 * (RH)) + hi) ^ swzb) << 4);                 \
    int vb1 = krow + ((((H) * 8 + 2 * (2 * (RH) + 1) + hi) ^ swzb) << 4);             \
    short8 vf00 = *(const short8*)((char*)Vl[CUR] + vb0);                             \
    short8 vf01 = *(const short8*)((char*)Vl[CUR] + vb0 + 8192);                      \
    short8 vf10 = *(const short8*)((char*)Vl[CUR] + vb1);                             \
    short8 vf11 = *(const short8*)((char*)Vl[CUR] + vb1 + 8192);                      \
    of0 = MFMA32(P0.s, vf00, of0);                                                    \
    of1 = MFMA32(P0.s, vf01, of1);                                                    \
    of0 = MFMA32(P1.s, vf10, of0);                                                    \
    of1 = MFMA32(P1.s, vf11, of1);                                                    \
  }

#define STEP128(CUR, PF)                                                              \
  {                                                                                   \
    if (PF) STAGE_ALL(CUR ^ 1);                                                       \
    floatx16 sfA = {}, sfB = {};                                                      \
    QK_Q(sfA, CUR, 0, 0);                                                             \
    QK_Q(sfB, CUR, 0, 1);                                                             \
    {                                                                                 \
      PAu p0, p1;                                                                     \
      EXPPACK(sfA, p0, p1);                                                           \
      PV_Q(p0, p1, CUR, 0, 0);                                                        \
    }                                                                                 \
    sfA = (floatx16){};                                                               \
    QK_Q(sfA, CUR, 1, 0);                                                             \
    {                                                                                 \
      PAu p0, p1;                                                                     \
      EXPPACK(sfB, p0, p1);                                                           \
      PV_Q(p0, p1, CUR, 0, 1);                                                        \
    }                                                                                 \
    sfB = (floatx16){};                                                               \
    QK_Q(sfB, CUR, 1, 1);                                                             \
    {                                                                                 \
      PAu p0, p1;                                                                     \
      EXPPACK(sfA, p0, p1);                                                           \
      PV_Q(p0, p1, CUR, 1, 0);                                                        \
    }                                                                                 \
    {                                                                                 \
      PAu p0, p1;                                                                     \
      EXPPACK(sfB, p0, p1);                                                           \
      PV_Q(p0, p1, CUR, 1, 1);                                                        \
    }                                                                                 \
    __syncthreads();                                                                  \
  }

  for (int it = 0; it < 8; ++it) {   // 16 kv-tiles of 128, 2 per iteration
    STEP128(0, 1);
    STEP128(1, it < 7);
  }

  // --- epilogue: complete rowsums and normalize.
  rs += __shfl_xor(rs, 32);          // full rowsum for q = l32 (both hi halves)
#pragma unroll
  for (int r = 0; r < 16; ++r) {
    int qloc = (r & 3) + 8 * (r >> 2) + 4 * hi;       // q index of of-frag row r
    float rsq = __shfl(rs, qloc);                      // rowsum for that q
    float rinv = 1.0f / rsq;
    int qrow = q0 + qloc;
    AO[base + (size_t)qrow * 1024 + l32]      = f2bf(of0[r] * rinv);
    AO[base + (size_t)qrow * 1024 + 32 + l32] = f2bf(of1[r] * rinv);
  }
#undef STAGE_ALL
#undef QK_Q
#undef EXPPACK
#undef PV_Q
#undef STEP128
}

// ---------- launch ----------
extern "C" void kernel_launch(void* const* d_in, const int* in_sizes, int n_in,
                              void* d_out, int out_size, void* d_ws, size_t ws_size,
                              hipStream_t stream) {
  const float* q  = (const float*)d_in[0];
  const float* k  = (const float*)d_in[1];
  const float* v  = (const float*)d_in[2];
  const float* Wq = (const float*)d_in[3];
  const float* bq = (const float*)d_in[4];
  const float* Wk = (const float*)d_in[5];
  const float* bk = (const float*)d_in[6];
  const float* Wv = (const float*)d_in[7];
  const float* bv = (const float*)d_in[8];
  const float* Wo = (const float*)d_in[9];
  const float* bo = (const float*)d_in[10];

  const size_t MB = 1ull << 20;
  char* ws = (char*)d_ws;
  uint16_t* XQ  = (uint16_t*)(ws + 0 * MB);    // 16MB x3, contiguous (cvt strides)
  uint16_t* XK  = (uint16_t*)(ws + 16 * MB);
  uint16_t* XV  = (uint16_t*)(ws + 32 * MB);
  uint16_t* WQb = (uint16_t*)(ws + 48 * MB);   // 2MB x4, contiguous (cvt strides)
  uint16_t* WKb = (uint16_t*)(ws + 50 * MB);
  uint16_t* WVb = (uint16_t*)(ws + 52 * MB);
  uint16_t* WOb = (uint16_t*)(ws + 54 * MB);
  uint16_t* QP  = (uint16_t*)(ws + 56 * MB);
  uint16_t* KP  = (uint16_t*)(ws + 72 * MB);
  uint16_t* VT  = (uint16_t*)(ws + 88 * MB);   // V projected + transposed, 16MB
  uint16_t* AO  = XQ;   // alias: XQ dead after QKV projection

  const float qscale = 0.125f * 1.4426950408889634f;  // softmax scale * log2e -> exp2

  cvt7_k<<<dim3(2048, 1, 7), dim3(256), 0, stream>>>(q, k, v, Wq, Wk, Wv, Wo, XQ, WQb);

  gemm_qkv_k<<<dim3(4, 32, 3), dim3(512), 0, stream>>>(
      XQ, XK, XV, WQb, WKb, WVb, bq, bk, bv, QP, KP, VT, qscale);

  attn_k<<<dim3(8, 64), dim3(512), 0, stream>>>(QP, KP, VT, AO);

  gemm_o_k<<<dim3(8, 32), dim3(512), 0, stream>>>(AO, WOb, bo, (float*)d_out);
}

// Round 18
// 194.170 us; speedup vs baseline: 1.0044x; 1.0044x over previous
//
#include <hip/hip_runtime.h>
#include <hip/hip_bf16.h>
#include <stdint.h>

// ---------- types ----------
typedef __attribute__((ext_vector_type(8))) short short8;      // 8 bf16 (MFMA A/B frag)
typedef __attribute__((ext_vector_type(4))) float floatx4;     // 16x16 C/D frag
typedef __attribute__((ext_vector_type(16))) float floatx16;   // 32x32 C/D frag
typedef __attribute__((ext_vector_type(4))) uint16_t ushort4v;

#define MFMA16(a, b, c) __builtin_amdgcn_mfma_f32_16x16x32_bf16((a), (b), (c), 0, 0, 0)
#define MFMA32(a, b, c) __builtin_amdgcn_mfma_f32_32x32x16_bf16((a), (b), (c), 0, 0, 0)

// async global->LDS, 16B per lane; LDS dest is wave-uniform base + lane*16
#define GLOAD_LDS16(g, l)                                                          \
  __builtin_amdgcn_global_load_lds(                                                \
      (const __attribute__((address_space(1))) uint32_t*)(g),                      \
      (__attribute__((address_space(3))) uint32_t*)(l), 16, 0, 0)

// packed f32x2 -> bf16x2
#define CVTPK(lo_, hi_, out_) \
  asm("v_cvt_pk_bf16_f32 %0, %1, %2" : "=v"(out_) : "v"(lo_), "v"(hi_))
// exchange a's high 32 lanes with b's low 32 lanes
#define SWAP32(a_, b_) \
  asm("v_permlane32_swap_b32 %0, %1" : "+v"(a_), "+v"(b_))

#define WAITVM(N)                                          \
  {                                                        \
    asm volatile("s_waitcnt vmcnt(" #N ")" ::: "memory");  \
    __builtin_amdgcn_sched_barrier(0);                     \
  }
#define SBAR                                               \
  {                                                        \
    __builtin_amdgcn_s_barrier();                          \
    __builtin_amdgcn_sched_barrier(0);                     \
  }

// fp32 -> bf16 round-to-nearest-even
__device__ __forceinline__ uint16_t f2bf(float x) {
  union { float f; uint32_t u; } c; c.f = x;
  return (uint16_t)((c.u + 0x7FFFu + ((c.u >> 16) & 1u)) >> 16);
}

// ---------- fp32 -> bf16 convert, all 7 tensors in one launch (z = 0..6) ----------
__global__ void cvt7_k(const float* __restrict__ q, const float* __restrict__ k,
                       const float* __restrict__ v, const float* __restrict__ w0,
                       const float* __restrict__ w1, const float* __restrict__ w2,
                       const float* __restrict__ w3, uint16_t* __restrict__ dstBig,
                       uint16_t* __restrict__ dstW) {
  const int z = blockIdx.z;
  const float* src;
  uint16_t* d;
  int n4;
  if (z < 3) {
    src = z == 0 ? q : (z == 1 ? k : v);
    d = dstBig + (size_t)z * 8388608;   // 16MB stride
    n4 = 2097152;
  } else {
    const int i = z - 3;
    src = i == 0 ? w0 : (i == 1 ? w1 : (i == 2 ? w2 : w3));
    d = dstW + (size_t)i * 1048576;     // 2MB stride
    n4 = 262144;
  }
  int stride = gridDim.x * blockDim.x;
  for (int i = blockIdx.x * blockDim.x + threadIdx.x; i < n4; i += stride) {
    float4 vv = ((const float4*)src)[i];
    ushort4v o;
    o.x = f2bf(vv.x); o.y = f2bf(vv.y); o.z = f2bf(vv.z); o.w = f2bf(vv.w);
    ((ushort4v*)d)[i] = o;
  }
}

// ======== GEMM A: 256x256 tile, per-wave 128x64, BK=64, 2-buf counted pipeline ====
// Schedule: compute(cur) -> SBAR -> stage kt+2 into cur (8 loads) -> vmcnt(8)
// (waits kt+1 only; kt+2 stays in flight) -> SBAR.
// LDS unit (R14-proven): 128 source rows x 64 k = 16KB; [64 r][16 slots x 16B],
// slot q of row r holds q0=q^(r&15): source row 64*(q0>>3)+r, kchunk q0&7.
// A = 2 units (rows 0-127,128-255); B = 2 units (cols 0-127,128-255). 32KB each/buf.
// MODE: 1 = bf16 out, 2 = bf16 V-transposed out.
template <int MODE>
__device__ __forceinline__ void gemm256sq_body(uint16_t* __restrict__ As,  // LDS 2*16384
                                               uint16_t* __restrict__ Bs,  // LDS 2*16384
                                               const uint16_t* __restrict__ A,
                                               const uint16_t* __restrict__ W,
                                               const float* __restrict__ bias,
                                               void* __restrict__ Cout, float scale,
                                               int brow, int bcol) {
  constexpr int N = 1024, K = 1024;
  const int t = threadIdx.x;
  const int l = t & 63, w = t >> 6;       // 8 waves
  const int l16 = l & 15, lhi = (l >> 4) & 3;
  const int wm = w >> 2, wn = w & 3;      // 2 M-waves x 4 N-waves; per-wave C 128x64

  // staging sources (advance +64 per K-tile); 4 issues each for A and B
  const uint16_t* pA[4];
  const uint16_t* pB[4];
#pragma unroll
  for (int i = 0; i < 4; ++i) {
    int cw = (i * 512 + t) & 1023;        // within-unit chunk
    int r = cw >> 4, q = cw & 15;
    int q0 = q ^ (r & 15);
    int srow = (i >> 1) * 128 + 64 * (q0 >> 3) + r;
    pA[i] = A + (size_t)(brow + srow) * K + (q0 & 7) * 8;
    pB[i] = W + (size_t)(bcol + srow) * K + (q0 & 7) * 8;
  }

#define G2_STAGE(BUF)                                                     \
  {                                                                       \
    _Pragma("unroll") for (int i = 0; i < 4; ++i) {                       \
      GLOAD_LDS16(pA[i], As + (BUF) * 16384 + i * 4096 + w * 512);        \
      GLOAD_LDS16(pB[i], Bs + (BUF) * 16384 + i * 4096 + w * 512);        \
      pA[i] += 64;                                                        \
      pB[i] += 64;                                                        \
    }                                                                     \
  }

  floatx4 acc[8][4] = {};

  // A-frag (m=0..7, ks): byte = wm*16384 + ((m&3)*16+l16)*256
  //                             + ((((m>>2)*8) + ks*4 + lhi) ^ l16)*16
  // B-frag (n=0..3, ks): byte = (wn>>1)*16384 + (n*16+l16)*256
  //                             + ((((wn&1)*8) + ks*4 + lhi) ^ l16)*16
#define G2_COMPUTE(BUF)                                                              \
  {                                                                                  \
    _Pragma("unroll") for (int ks = 0; ks < 2; ++ks) {                               \
      short8 a[8], b[4];                                                             \
      _Pragma("unroll") for (int m = 0; m < 8; ++m)                                  \
        a[m] = *(const short8*)((const char*)As + (BUF) * 32768 + wm * 16384 +       \
            ((m & 3) * 16 + l16) * 256 + ((((m >> 2) * 8 + ks * 4 + lhi) ^ l16) << 4)); \
      _Pragma("unroll") for (int n = 0; n < 4; ++n)                                  \
        b[n] = *(const short8*)((const char*)Bs + (BUF) * 32768 + (wn >> 1) * 16384 + \
            (n * 16 + l16) * 256 + ((((wn & 1) * 8 + ks * 4 + lhi) ^ l16) << 4));    \
      __builtin_amdgcn_s_setprio(1);                                                 \
      _Pragma("unroll") for (int m = 0; m < 8; ++m)                                  \
        _Pragma("unroll") for (int n = 0; n < 4; ++n)                                \
          acc[m][n] = MFMA16(a[m], b[n], acc[m][n]);                                 \
      __builtin_amdgcn_s_setprio(0);                                                 \
    }                                                                                \
  }

  // prologue: stage kt0 -> buf0, kt1 -> buf1; wait kt0 (8 of 16 oldest)
  G2_STAGE(0);
  G2_STAGE(1);
  WAITVM(8);
  SBAR;

  // kt = 0..13 (stage kt+2 = 2..15 into the buffer just read)
#pragma unroll 1
  for (int g = 0; g < 7; ++g) {
    G2_COMPUTE(0); SBAR; G2_STAGE(0); WAITVM(8); SBAR;
    G2_COMPUTE(1); SBAR; G2_STAGE(1); WAITVM(8); SBAR;
  }
  // kt=14 (buf0); then drain kt15's loads; kt=15 (buf1)
  G2_COMPUTE(0);
  WAITVM(0);
  SBAR;
  G2_COMPUTE(1);

  // ---- epilogue ----
#pragma unroll
  for (int n = 0; n < 4; ++n) {
    int col = bcol + wn * 64 + n * 16 + l16;
    float bv = bias[col];
    if (MODE == 2) {
      int h = col >> 6, d = col & 63;
#pragma unroll
      for (int m = 0; m < 8; ++m) {
        int row = brow + wm * 128 + m * 16 + lhi * 4;   // j=0 row
        int b_ = row >> 11, s = row & 2047;
        union { uint16_t u[4]; ushort4v v; } pk4;
#pragma unroll
        for (int j = 0; j < 4; ++j) pk4.u[j] = f2bf(acc[m][n][j] + bv);
        *(ushort4v*)((uint16_t*)Cout + (size_t)(b_ * 16 + h) * 131072 + (size_t)d * 2048 + s) = pk4.v;
      }
    } else {
#pragma unroll
      for (int m = 0; m < 8; ++m) {
#pragma unroll
        for (int j = 0; j < 4; ++j) {
          int row = brow + wm * 128 + m * 16 + lhi * 4 + j;
          ((uint16_t*)Cout)[(size_t)row * N + col] = f2bf((acc[m][n][j] + bv) * scale);
        }
      }
    }
  }
#undef G2_STAGE
#undef G2_COMPUTE
}

// fused Q/K/V projections: 384 blocks (4x, 32y, 3z), XCD-chunked; V pre-transposed.
// amdgpu_waves_per_eu(2,2): target exactly 2 waves/EU -> 256 VGPR budget.
// R17 evidence: without it the allocator pinned 128 VGPR and spilled acc
// (WRITE_SIZE 49->78MB). 8-wave block at 1 block/CU (128KB LDS) = 2 waves/EU
// anyway, so nothing is lost.
__global__ __launch_bounds__(512, 1) __attribute__((amdgpu_waves_per_eu(2, 2)))
void gemm_qkv_k(const uint16_t* __restrict__ XQ, const uint16_t* __restrict__ XK,
                const uint16_t* __restrict__ XV, const uint16_t* __restrict__ WQ,
                const uint16_t* __restrict__ WK, const uint16_t* __restrict__ WV,
                const float* __restrict__ bq, const float* __restrict__ bk,
                const float* __restrict__ bv, uint16_t* __restrict__ QP,
                uint16_t* __restrict__ KP, uint16_t* __restrict__ VT, float qscale) {
  __shared__ uint16_t As[2 * 16384];   // 64KB
  __shared__ uint16_t Bs[2 * 16384];   // 64KB
  const int f = (blockIdx.z * 32 + blockIdx.y) * 4 + blockIdx.x;
  const int virt = (f & 7) * 48 + (f >> 3);     // 384 = 8*48, bijective
  const int vz = virt >> 7;                     // 128 tiles per projection
  const int rem = virt & 127;
  const int vy = rem >> 2, vx = rem & 3;

  if (vz == 0)      gemm256sq_body<1>(As, Bs, XQ, WQ, bq, QP, qscale, vy * 256, vx * 256);
  else if (vz == 1) gemm256sq_body<1>(As, Bs, XK, WK, bk, KP, 1.0f,  vy * 256, vx * 256);
  else              gemm256sq_body<2>(As, Bs, XV, WV, bv, VT, 1.0f,  vy * 256, vx * 256);
}

// ======== GEMM B (proven R14): 256x128 tile, BK=64, 3-buffer counted pipeline =====
__device__ __forceinline__ void gemm256_body_f32(uint16_t* __restrict__ As,   // 3*16384
                                                 uint16_t* __restrict__ Bs,   // 3*8192
                                                 const uint16_t* __restrict__ A,
                                                 const uint16_t* __restrict__ W,
                                                 const float* __restrict__ bias,
                                                 float* __restrict__ Cout,
                                                 int brow, int bcol) {
  constexpr int N = 1024, K = 1024;
  const int t = threadIdx.x;
  const int l = t & 63, w = t >> 6;
  const int l16 = l & 15, lhi = (l >> 4) & 3;
  const int wm = w >> 1, wn = w & 1;

  const uint16_t* pA[4];
  const uint16_t* pB[2];
#pragma unroll
  for (int i = 0; i < 4; ++i) {
    int cw = (i * 512 + t) & 1023;
    int r = cw >> 4, q = cw & 15;
    int q0 = q ^ (r & 15);
    pA[i] = A + (size_t)(brow + (i >> 1) * 128 + 64 * (q0 >> 3) + r) * K + (q0 & 7) * 8;
  }
#pragma unroll
  for (int i = 0; i < 2; ++i) {
    int c = i * 512 + t;
    int r = c >> 4, q = c & 15;
    int q0 = q ^ (r & 15);
    pB[i] = W + (size_t)(bcol + 64 * (q0 >> 3) + r) * K + (q0 & 7) * 8;
  }

#define G_STAGE(BUF)                                                      \
  {                                                                       \
    _Pragma("unroll") for (int i = 0; i < 4; ++i) {                       \
      GLOAD_LDS16(pA[i], As + (BUF) * 16384 + i * 4096 + w * 512);        \
      pA[i] += 64;                                                        \
    }                                                                     \
    _Pragma("unroll") for (int i = 0; i < 2; ++i) {                       \
      GLOAD_LDS16(pB[i], Bs + (BUF) * 8192 + i * 4096 + w * 512);         \
      pB[i] += 64;                                                        \
    }                                                                     \
  }

  floatx4 acc[4][4] = {};

#define G_COMPUTE(BUF)                                                               \
  {                                                                                  \
    short8 a[4][2], b[4][2];                                                         \
    _Pragma("unroll") for (int m = 0; m < 4; ++m)                                    \
      _Pragma("unroll") for (int ks = 0; ks < 2; ++ks)                               \
        a[m][ks] = *(const short8*)((const char*)(As + (BUF) * 16384) +              \
            (wm >> 1) * 16384 +                                                      \
            (m * 16 + l16) * 256 + ((((wm & 1) * 8 + ks * 4 + lhi) ^ l16) << 4));    \
    _Pragma("unroll") for (int n = 0; n < 4; ++n)                                    \
      _Pragma("unroll") for (int ks = 0; ks < 2; ++ks)                               \
        b[n][ks] = *(const short8*)((const char*)(Bs + (BUF) * 8192) +               \
            (n * 16 + l16) * 256 + (((wn * 8 + ks * 4 + lhi) ^ l16) << 4));          \
    __builtin_amdgcn_s_setprio(1);                                                   \
    _Pragma("unroll") for (int ks = 0; ks < 2; ++ks)                                 \
      _Pragma("unroll") for (int m = 0; m < 4; ++m)                                  \
        _Pragma("unroll") for (int n = 0; n < 4; ++n)                                \
          acc[m][n] = MFMA16(a[m][ks], b[n][ks], acc[m][n]);                         \
    __builtin_amdgcn_s_setprio(0);                                                   \
  }

#define G_STEP(RD, ST)   \
  {                      \
    G_STAGE(ST);         \
    G_COMPUTE(RD);       \
    WAITVM(6);           \
    SBAR;                \
  }

  G_STAGE(0);
  G_STAGE(1);
  WAITVM(6);
  SBAR;

#pragma unroll 1
  for (int g = 0; g < 4; ++g) {
    G_STEP(0, 2);
    G_STEP(1, 0);
    G_STEP(2, 1);
  }
  G_STEP(0, 2);
  G_STEP(1, 0);
  G_COMPUTE(2);
  WAITVM(0);
  SBAR;
  G_COMPUTE(0);

#pragma unroll
  for (int n = 0; n < 4; ++n) {
    int col = bcol + wn * 64 + n * 16 + l16;
    float bv = bias[col];
#pragma unroll
    for (int m = 0; m < 4; ++m) {
#pragma unroll
      for (int j = 0; j < 4; ++j) {
        int row = brow + wm * 64 + m * 16 + lhi * 4 + j;
        Cout[(size_t)row * N + col] = acc[m][n][j] + bv;
      }
    }
  }
#undef G_STAGE
#undef G_COMPUTE
#undef G_STEP
}

// output projection: 256 blocks (8x, 32y), XCD-chunked.
__global__ __launch_bounds__(512, 1)
void gemm_o_k(const uint16_t* __restrict__ A, const uint16_t* __restrict__ W,
              const float* __restrict__ bias, float* __restrict__ Cout) {
  __shared__ uint16_t As[3 * 16384];
  __shared__ uint16_t Bs[3 * 8192];
  const int f = blockIdx.y * 8 + blockIdx.x;
  const int virt = (f & 7) * 32 + (f >> 3);
  const int vy = virt >> 3, vx = virt & 7;
  gemm256_body_f32(As, Bs, A, W, bias, Cout, vy * 256, vx * 128);
}

// ---------- flash attention: quarter-pipelined (QK_next ∥ exp/pack_cur) ----------
__global__ __launch_bounds__(512, 2)
void attn_k(const uint16_t* __restrict__ Qp, const uint16_t* __restrict__ Kp,
            const uint16_t* __restrict__ Vt, uint16_t* __restrict__ AO) {
  __shared__ uint16_t Kl[2][64 * 128];   // 16KB per buffer
  __shared__ uint16_t Vl[2][64 * 128];   // 16KB per buffer

  const int t = threadIdx.x;
  const int l = t & 63, w = t >> 6;       // w = 0..7
  const int l32 = l & 31, hi = l >> 5;

  // XCD-chunked swizzle: 512 blocks, 64 per XCD -> 8 contiguous bh groups each.
  const int f = blockIdx.y * 8 + blockIdx.x;
  const int virt = (f & 7) * 64 + (f >> 3);
  const int vx = virt & 7;     // q-block (256 q each)
  const int vy = virt >> 3;    // bh

  const int q0 = vx * 256 + w * 32;
  const size_t base = (size_t)(vy >> 4) * 2048 * 1024 + (size_t)(vy & 15) * 64;
  const size_t vbg = (size_t)vy * 131072;  // (b*16+h)*64*2048

  union PAu { uint32_t u[4]; short8 s; };

  // staging: 1024 chunks per matrix per tile; 512 threads -> 2 issues each.
  const uint16_t* pK[2];
  const uint16_t* pV[2];
#pragma unroll
  for (int i = 0; i < 2; ++i) {
    int c = i * 512 + t;
    int r = c >> 4, qs = c & 15;
    int q0c = qs ^ (r & 15);
    pK[i] = Kp + base + (size_t)(64 * (q0c >> 3) + r) * 1024 + (q0c & 7) * 8;
    pV[i] = Vt + vbg + (size_t)r * 2048 + q0c * 8;
  }

#define STAGE_ALL(NB)                                                 \
  {                                                                   \
    _Pragma("unroll") for (int i = 0; i < 2; ++i) {                   \
      GLOAD_LDS16(pK[i], &Kl[NB][(size_t)(i * 512 + w * 64) * 8]);    \
      GLOAD_LDS16(pV[i], &Vl[NB][(size_t)(i * 512 + w * 64) * 8]);    \
      pK[i] += 131072;  /* +128 source rows */                        \
      pV[i] += 128;     /* +128 s columns  */                        \
    }                                                                 \
  }

  // Q B-frags: lane holds Q[q0 + l32][k = ks*16 + hi*8 + i]
  short8 qf[4];
#pragma unroll
  for (int ks = 0; ks < 4; ++ks)
    qf[ks] = *(const short8*)(Qp + base + (size_t)(q0 + l32) * 1024 + ks * 16 + hi * 8);

  floatx16 of0 = {}, of1 = {};   // O[q][d] C-frags
  float rs = 0.f;                // per-lane partial rowsum

  const int swzb = (l32 & 15);
  const int krow = l32 * 256;    // byte base of LDS row l32 (row +32 = +8192)

  STAGE_ALL(0);
  __syncthreads();

#define QK_Q(SF, CUR, H, RH)                                                          \
  {                                                                                   \
    _Pragma("unroll") for (int ks = 0; ks < 4; ++ks) {                                \
      int kbyte = krow + (RH) * 8192 + ((((H) * 8 + 2 * ks + hi) ^ swzb) << 4);       \
      short8 kf = *(const short8*)((char*)Kl[CUR] + kbyte);                           \
      SF = MFMA32(kf, qf[ks], SF);                                                    \
    }                                                                                 \
  }

#define EXPPACK(SF, P0, P1)                                                           \
  {                                                                                   \
    _Pragma("unroll") for (int r = 0; r < 16; ++r) {                                  \
      SF[r] = __builtin_amdgcn_exp2f(SF[r]);                                          \
      rs += SF[r];                                                                    \
    }                                                                                 \
    uint32_t a0, a1, b0, b1;                                                          \
    CVTPK(SF[0], SF[1], a0); CVTPK(SF[2], SF[3], a1);                                 \
    CVTPK(SF[4], SF[5], b0); CVTPK(SF[6], SF[7], b1);                                 \
    SWAP32(a0, b0); SWAP32(a1, b1);                                                   \
    P0.u[0] = a0; P0.u[1] = a1; P0.u[2] = b0; P0.u[3] = b1;                           \
    CVTPK(SF[8], SF[9], a0); CVTPK(SF[10], SF[11], a1);                               \
    CVTPK(SF[12], SF[13], b0); CVTPK(SF[14], SF[15], b1);                             \
    SWAP32(a0, b0); SWAP32(a1, b1);                                                   \
    P1.u[0] = a0; P1.u[1] = a1; P1.u[2] = b0; P1.u[3] = b1;                           \
  }

#define PV_Q(P0, P1, CUR, H, RH)                                                      \
  {                                                                                   \
    int vb0 = krow + ((((H) * 8 + 2 * (2 * (RH)) + hi) ^ swzb) << 4);                 \
    int vb1 = krow + ((((H) * 8 + 2 * (2 * (RH) + 1) + hi) ^ swzb) << 4);             \
    short8 vf00 = *(const short8*)((char*)Vl[CUR] + vb0);                             \
    short8 vf01 = *(const short8*)((char*)Vl[CUR] + vb0 + 8192);                      \
    short8 vf10 = *(const short8*)((char*)Vl[CUR] + vb1);                             \
    short8 vf11 = *(const short8*)((char*)Vl[CUR] + vb1 + 8192);                      \
    of0 = MFMA32(P0.s, vf00, of0);                                                    \
    of1 = MFMA32(P0.s, vf01, of1);                                                    \
    of0 = MFMA32(P1.s, vf10, of0);                                                    \
    of1 = MFMA32(P1.s, vf11, of1);                                                    \
  }

#define STEP128(CUR, PF)                                                              \
  {                                                                                   \
    if (PF) STAGE_ALL(CUR ^ 1);                                                       \
    floatx16 sfA = {}, sfB = {};                                                      \
    QK_Q(sfA, CUR, 0, 0);                                                             \
    QK_Q(sfB, CUR, 0, 1);                                                             \
    {                                                                                 \
      PAu p0, p1;                                                                     \
      EXPPACK(sfA, p0, p1);                                                           \
      PV_Q(p0, p1, CUR, 0, 0);                                                        \
    }                                                                                 \
    sfA = (floatx16){};                                                               \
    QK_Q(sfA, CUR, 1, 0);                                                             \
    {                                                                                 \
      PAu p0, p1;                                                                     \
      EXPPACK(sfB, p0, p1);                                                           \
      PV_Q(p0, p1, CUR, 0, 1);                                                        \
    }                                                                                 \
    sfB = (floatx16){};                                                               \
    QK_Q(sfB, CUR, 1, 1);                                                             \
    {                                                                                 \
      PAu p0, p1;                                                                     \
      EXPPACK(sfA, p0, p1);                                                           \
      PV_Q(p0, p1, CUR, 1, 0);                                                        \
    }                                                                                 \
    {                                                                                 \
      PAu p0, p1;                                                                     \
      EXPPACK(sfB, p0, p1);                                                           \
      PV_Q(p0, p1, CUR, 1, 1);                                                        \
    }                                                                                 \
    __syncthreads();                                                                  \
  }

  for (int it = 0; it < 8; ++it) {   // 16 kv-tiles of 128, 2 per iteration
    STEP128(0, 1);
    STEP128(1, it < 7);
  }

  // --- epilogue: complete rowsums and normalize.
  rs += __shfl_xor(rs, 32);          // full rowsum for q = l32 (both hi halves)
#pragma unroll
  for (int r = 0; r < 16; ++r) {
    int qloc = (r & 3) + 8 * (r >> 2) + 4 * hi;       // q index of of-frag row r
    float rsq = __shfl(rs, qloc);                      // rowsum for that q
    float rinv = 1.0f / rsq;
    int qrow = q0 + qloc;
    AO[base + (size_t)qrow * 1024 + l32]      = f2bf(of0[r] * rinv);
    AO[base + (size_t)qrow * 1024 + 32 + l32] = f2bf(of1[r] * rinv);
  }
#undef STAGE_ALL
#undef QK_Q
#undef EXPPACK
#undef PV_Q
#undef STEP128
}

// ---------- launch ----------
extern "C" void kernel_launch(void* const* d_in, const int* in_sizes, int n_in,
                              void* d_out, int out_size, void* d_ws, size_t ws_size,
                              hipStream_t stream) {
  const float* q  = (const float*)d_in[0];
  const float* k  = (const float*)d_in[1];
  const float* v  = (const float*)d_in[2];
  const float* Wq = (const float*)d_in[3];
  const float* bq = (const float*)d_in[4];
  const float* Wk = (const float*)d_in[5];
  const float* bk = (const float*)d_in[6];
  const float* Wv = (const float*)d_in[7];
  const float* bv = (const float*)d_in[8];
  const float* Wo = (const float*)d_in[9];
  const float* bo = (const float*)d_in[10];

  const size_t MB = 1ull << 20;
  char* ws = (char*)d_ws;
  uint16_t* XQ  = (uint16_t*)(ws + 0 * MB);    // 16MB x3, contiguous (cvt strides)
  uint16_t* XK  = (uint16_t*)(ws + 16 * MB);
  uint16_t* XV  = (uint16_t*)(ws + 32 * MB);
  uint16_t* WQb = (uint16_t*)(ws + 48 * MB);   // 2MB x4, contiguous (cvt strides)
  uint16_t* WKb = (uint16_t*)(ws + 50 * MB);
  uint16_t* WVb = (uint16_t*)(ws + 52 * MB);
  uint16_t* WOb = (uint16_t*)(ws + 54 * MB);
  uint16_t* QP  = (uint16_t*)(ws + 56 * MB);
  uint16_t* KP  = (uint16_t*)(ws + 72 * MB);
  uint16_t* VT  = (uint16_t*)(ws + 88 * MB);   // V projected + transposed, 16MB
  uint16_t* AO  = XQ;   // alias: XQ dead after QKV projection

  const float qscale = 0.125f * 1.4426950408889634f;  // softmax scale * log2e -> exp2

  cvt7_k<<<dim3(2048, 1, 7), dim3(256), 0, stream>>>(q, k, v, Wq, Wk, Wv, Wo, XQ, WQb);

  gemm_qkv_k<<<dim3(4, 32, 3), dim3(512), 0, stream>>>(
      XQ, XK, XV, WQb, WKb, WVb, bq, bk, bv, QP, KP, VT, qscale);

  attn_k<<<dim3(8, 64), dim3(512), 0, stream>>>(QP, KP, VT, AO);

  gemm_o_k<<<dim3(8, 32), dim3(512), 0, stream>>>(AO, WOb, bo, (float*)d_out);
}

// Round 19
// 186.414 us; speedup vs baseline: 1.0462x; 1.0416x over previous
//
#include <hip/hip_runtime.h>
#include <hip/hip_bf16.h>
#include <stdint.h>

// ---------- types ----------
typedef __attribute__((ext_vector_type(8))) short short8;      // 8 bf16 (MFMA A/B frag)
typedef __attribute__((ext_vector_type(4))) float floatx4;     // 16x16 C/D frag
typedef __attribute__((ext_vector_type(16))) float floatx16;   // 32x32 C/D frag
typedef __attribute__((ext_vector_type(4))) uint16_t ushort4v;

#define MFMA16(a, b, c) __builtin_amdgcn_mfma_f32_16x16x32_bf16((a), (b), (c), 0, 0, 0)
#define MFMA32(a, b, c) __builtin_amdgcn_mfma_f32_32x32x16_bf16((a), (b), (c), 0, 0, 0)

// async global->LDS, 16B per lane; LDS dest is wave-uniform base + lane*16
#define GLOAD_LDS16(g, l)                                                          \
  __builtin_amdgcn_global_load_lds(                                                \
      (const __attribute__((address_space(1))) uint32_t*)(g),                      \
      (__attribute__((address_space(3))) uint32_t*)(l), 16, 0, 0)

// packed f32x2 -> bf16x2
#define CVTPK(lo_, hi_, out_) \
  asm("v_cvt_pk_bf16_f32 %0, %1, %2" : "=v"(out_) : "v"(lo_), "v"(hi_))
// exchange a's high 32 lanes with b's low 32 lanes
#define SWAP32(a_, b_) \
  asm("v_permlane32_swap_b32 %0, %1" : "+v"(a_), "+v"(b_))

#define WAITVM(N)                                          \
  {                                                        \
    asm volatile("s_waitcnt vmcnt(" #N ")" ::: "memory");  \
    __builtin_amdgcn_sched_barrier(0);                     \
  }
#define SBAR                                               \
  {                                                        \
    __builtin_amdgcn_s_barrier();                          \
    __builtin_amdgcn_sched_barrier(0);                     \
  }

// fp32 -> bf16 round-to-nearest-even
__device__ __forceinline__ uint16_t f2bf(float x) {
  union { float f; uint32_t u; } c; c.f = x;
  return (uint16_t)((c.u + 0x7FFFu + ((c.u >> 16) & 1u)) >> 16);
}

// ---------- fp32 -> bf16 convert, all 7 tensors in one launch (z = 0..6) ----------
__global__ void cvt7_k(const float* __restrict__ q, const float* __restrict__ k,
                       const float* __restrict__ v, const float* __restrict__ w0,
                       const float* __restrict__ w1, const float* __restrict__ w2,
                       const float* __restrict__ w3, uint16_t* __restrict__ dstBig,
                       uint16_t* __restrict__ dstW) {
  const int z = blockIdx.z;
  const float* src;
  uint16_t* d;
  int n4;
  if (z < 3) {
    src = z == 0 ? q : (z == 1 ? k : v);
    d = dstBig + (size_t)z * 8388608;   // 16MB stride
    n4 = 2097152;
  } else {
    const int i = z - 3;
    src = i == 0 ? w0 : (i == 1 ? w1 : (i == 2 ? w2 : w3));
    d = dstW + (size_t)i * 1048576;     // 2MB stride
    n4 = 262144;
  }
  int stride = gridDim.x * blockDim.x;
  for (int i = blockIdx.x * blockDim.x + threadIdx.x; i < n4; i += stride) {
    float4 vv = ((const float4*)src)[i];
    ushort4v o;
    o.x = f2bf(vv.x); o.y = f2bf(vv.y); o.z = f2bf(vv.z); o.w = f2bf(vv.w);
    ((ushort4v*)d)[i] = o;
  }
}

// ---------- GEMM: 256x128 tile, BK=64, 8 waves, 3-buffer counted-vmcnt pipeline ----
// LDS declared in the CALLER kernel (single allocation) and passed in.
// Per K-tile kt: stage kt+2 -> buf[(kt+2)%3] (6 gload_lds), compute buf[kt%3],
// s_waitcnt vmcnt(6) (kt+1's 6 loads are the oldest; fresh loads stay in flight),
// raw s_barrier (no vmcnt(0) drain).
// LDS half-unit (R6/R11 pattern): [64 r][16 slots x 16B]; slot q of row r holds
// q0 = q^(r&15): source row 64*(q0>>3)+r, kchunk q0&7. Conflict-free (counters: 0).
// NOTE (R17/R18 post-mortem): per-wave 128x64 / 256x256-tile variants spill —
// this toolchain pins 512-thread kernels at 128 VGPR regardless of launch_bounds
// or amdgpu_waves_per_eu hints. Keep per-wave 64x64 (acc = 64 VGPR).
// MODE: 0 = f32 out, 1 = bf16 out, 2 = bf16 V-transposed out.
template <int MODE>
__device__ __forceinline__ void gemm256_body(uint16_t* __restrict__ As,   // LDS, 3*16384
                                             uint16_t* __restrict__ Bs,   // LDS, 3*8192
                                             const uint16_t* __restrict__ A,
                                             const uint16_t* __restrict__ W,
                                             const float* __restrict__ bias,
                                             void* __restrict__ Cout, float scale,
                                             int brow, int bcol) {
  constexpr int N = 1024, K = 1024;
  const int t = threadIdx.x;
  const int l = t & 63, w = t >> 6;       // 8 waves
  const int l16 = l & 15, lhi = (l >> 4) & 3;
  const int wm = w >> 1, wn = w & 1;      // 4 M-waves x 2 N-waves; per-wave C 64x64

  // staging source pointers (advance +64 per K-tile)
  const uint16_t* pA[4];
  const uint16_t* pB[2];
#pragma unroll
  for (int i = 0; i < 4; ++i) {
    int cw = (i * 512 + t) & 1023;
    int r = cw >> 4, q = cw & 15;
    int q0 = q ^ (r & 15);
    pA[i] = A + (size_t)(brow + (i >> 1) * 128 + 64 * (q0 >> 3) + r) * K + (q0 & 7) * 8;
  }
#pragma unroll
  for (int i = 0; i < 2; ++i) {
    int c = i * 512 + t;
    int r = c >> 4, q = c & 15;
    int q0 = q ^ (r & 15);
    pB[i] = W + (size_t)(bcol + 64 * (q0 >> 3) + r) * K + (q0 & 7) * 8;
  }

#define G_STAGE(BUF)                                                      \
  {                                                                       \
    _Pragma("unroll") for (int i = 0; i < 4; ++i) {                       \
      GLOAD_LDS16(pA[i], As + (BUF) * 16384 + i * 4096 + w * 512);        \
      pA[i] += 64;                                                        \
    }                                                                     \
    _Pragma("unroll") for (int i = 0; i < 2; ++i) {                       \
      GLOAD_LDS16(pB[i], Bs + (BUF) * 8192 + i * 4096 + w * 512);         \
      pB[i] += 64;                                                        \
    }                                                                     \
  }

  floatx4 acc[4][4] = {};

  // A-frag (m,ks): byte = (wm>>1)*16384 + (m*16+l16)*256 + (((wm&1)*8+ks*4+lhi)^l16)*16
  // B-frag (n,ks): byte = (n*16+l16)*256 + ((wn*8+ks*4+lhi)^l16)*16
#define G_COMPUTE(BUF)                                                               \
  {                                                                                  \
    short8 a[4][2], b[4][2];                                                         \
    _Pragma("unroll") for (int m = 0; m < 4; ++m)                                    \
      _Pragma("unroll") for (int ks = 0; ks < 2; ++ks)                               \
        a[m][ks] = *(const short8*)((const char*)(As + (BUF) * 16384) +              \
            (wm >> 1) * 16384 +                                                      \
            (m * 16 + l16) * 256 + ((((wm & 1) * 8 + ks * 4 + lhi) ^ l16) << 4));    \
    _Pragma("unroll") for (int n = 0; n < 4; ++n)                                    \
      _Pragma("unroll") for (int ks = 0; ks < 2; ++ks)                               \
        b[n][ks] = *(const short8*)((const char*)(Bs + (BUF) * 8192) +               \
            (n * 16 + l16) * 256 + (((wn * 8 + ks * 4 + lhi) ^ l16) << 4));          \
    __builtin_amdgcn_s_setprio(1);                                                   \
    _Pragma("unroll") for (int ks = 0; ks < 2; ++ks)                                 \
      _Pragma("unroll") for (int m = 0; m < 4; ++m)                                  \
        _Pragma("unroll") for (int n = 0; n < 4; ++n)                                \
          acc[m][n] = MFMA16(a[m][ks], b[n][ks], acc[m][n]);                         \
    __builtin_amdgcn_s_setprio(0);                                                   \
  }

#define G_STEP(RD, ST)   \
  {                      \
    G_STAGE(ST);         \
    G_COMPUTE(RD);       \
    WAITVM(6);           \
    SBAR;                \
  }

  // prologue: stage kt=0,1; wait kt0 resident (6 of 12 oldest)
  G_STAGE(0);
  G_STAGE(1);
  WAITVM(6);
  SBAR;

  // kt = 0..11 (stage kt+2 = 2..13)
#pragma unroll 1
  for (int g = 0; g < 4; ++g) {
    G_STEP(0, 2);
    G_STEP(1, 0);
    G_STEP(2, 1);
  }
  G_STEP(0, 2);   // kt=12, stage 14
  G_STEP(1, 0);   // kt=13, stage 15
  // kt=14: no more staging; drain kt15's loads
  G_COMPUTE(2);
  WAITVM(0);
  SBAR;
  // kt=15
  G_COMPUTE(0);

  // ---- epilogue ----
#pragma unroll
  for (int n = 0; n < 4; ++n) {
    int col = bcol + wn * 64 + n * 16 + l16;
    float bv = bias[col];
    if (MODE == 2) {
      int h = col >> 6, d = col & 63;
#pragma unroll
      for (int m = 0; m < 4; ++m) {
        int row = brow + wm * 64 + m * 16 + lhi * 4;   // j=0 row
        int b_ = row >> 11, s = row & 2047;
        union { uint16_t u[4]; ushort4v v; } pk4;
#pragma unroll
        for (int j = 0; j < 4; ++j) pk4.u[j] = f2bf(acc[m][n][j] + bv);
        *(ushort4v*)((uint16_t*)Cout + (size_t)(b_ * 16 + h) * 131072 + (size_t)d * 2048 + s) = pk4.v;
      }
    } else {
#pragma unroll
      for (int m = 0; m < 4; ++m) {
#pragma unroll
        for (int j = 0; j < 4; ++j) {
          int row = brow + wm * 64 + m * 16 + lhi * 4 + j;
          float v = (acc[m][n][j] + bv) * scale;
          if (MODE == 1)
            ((uint16_t*)Cout)[(size_t)row * N + col] = f2bf(v);
          else
            ((float*)Cout)[(size_t)row * N + col] = v;
        }
      }
    }
  }
#undef G_STAGE
#undef G_COMPUTE
#undef G_STEP
}

// fused Q/K/V projections: 768 blocks (8x, 32y, 3z), XCD-chunked; V pre-transposed.
__global__ __launch_bounds__(512, 1)
void gemm_qkv_k(const uint16_t* __restrict__ XQ, const uint16_t* __restrict__ XK,
                const uint16_t* __restrict__ XV, const uint16_t* __restrict__ WQ,
                const uint16_t* __restrict__ WK, const uint16_t* __restrict__ WV,
                const float* __restrict__ bq, const float* __restrict__ bk,
                const float* __restrict__ bv, uint16_t* __restrict__ QP,
                uint16_t* __restrict__ KP, uint16_t* __restrict__ VT, float qscale) {
  __shared__ uint16_t As[3 * 16384];   // 96KB
  __shared__ uint16_t Bs[3 * 8192];    // 48KB
  const int f = (blockIdx.z * 32 + blockIdx.y) * 8 + blockIdx.x;
  const int virt = (f & 7) * 96 + (f >> 3);     // 768 = 8*96, bijective
  const int vz = virt >> 8;
  const int rem = virt & 255;
  const int vy = rem >> 3, vx = rem & 7;

  if (vz == 0)      gemm256_body<1>(As, Bs, XQ, WQ, bq, QP, qscale, vy * 256, vx * 128);
  else if (vz == 1) gemm256_body<1>(As, Bs, XK, WK, bk, KP, 1.0f,  vy * 256, vx * 128);
  else              gemm256_body<2>(As, Bs, XV, WV, bv, VT, 1.0f,  vy * 256, vx * 128);
}

// output projection: 256 blocks (8x, 32y), XCD-chunked.
__global__ __launch_bounds__(512, 1)
void gemm_o_k(const uint16_t* __restrict__ A, const uint16_t* __restrict__ W,
              const float* __restrict__ bias, float* __restrict__ Cout) {
  __shared__ uint16_t As[3 * 16384];
  __shared__ uint16_t Bs[3 * 8192];
  const int f = blockIdx.y * 8 + blockIdx.x;
  const int virt = (f & 7) * 32 + (f >> 3);
  const int vy = virt >> 3, vx = virt & 7;
  gemm256_body<0>(As, Bs, A, W, bias, Cout, 1.0f, vy * 256, vx * 128);
}

// ---------- flash attention: quarter-pipelined (QK_next ∥ exp/pack_cur) ----------
__global__ __launch_bounds__(512, 2)
void attn_k(const uint16_t* __restrict__ Qp, const uint16_t* __restrict__ Kp,
            const uint16_t* __restrict__ Vt, uint16_t* __restrict__ AO) {
  __shared__ uint16_t Kl[2][64 * 128];   // 16KB per buffer
  __shared__ uint16_t Vl[2][64 * 128];   // 16KB per buffer

  const int t = threadIdx.x;
  const int l = t & 63, w = t >> 6;       // w = 0..7
  const int l32 = l & 31, hi = l >> 5;

  // XCD-chunked swizzle: 512 blocks, 64 per XCD -> 8 contiguous bh groups each.
  const int f = blockIdx.y * 8 + blockIdx.x;
  const int virt = (f & 7) * 64 + (f >> 3);
  const int vx = virt & 7;     // q-block (256 q each)
  const int vy = virt >> 3;    // bh

  const int q0 = vx * 256 + w * 32;
  const size_t base = (size_t)(vy >> 4) * 2048 * 1024 + (size_t)(vy & 15) * 64;
  const size_t vbg = (size_t)vy * 131072;  // (b*16+h)*64*2048

  union PAu { uint32_t u[4]; short8 s; };

  // staging: 1024 chunks per matrix per tile; 512 threads -> 2 issues each.
  const uint16_t* pK[2];
  const uint16_t* pV[2];
#pragma unroll
  for (int i = 0; i < 2; ++i) {
    int c = i * 512 + t;
    int r = c >> 4, qs = c & 15;
    int q0c = qs ^ (r & 15);
    pK[i] = Kp + base + (size_t)(64 * (q0c >> 3) + r) * 1024 + (q0c & 7) * 8;
    pV[i] = Vt + vbg + (size_t)r * 2048 + q0c * 8;
  }

#define STAGE_ALL(NB)                                                 \
  {                                                                   \
    _Pragma("unroll") for (int i = 0; i < 2; ++i) {                   \
      GLOAD_LDS16(pK[i], &Kl[NB][(size_t)(i * 512 + w * 64) * 8]);    \
      GLOAD_LDS16(pV[i], &Vl[NB][(size_t)(i * 512 + w * 64) * 8]);    \
      pK[i] += 131072;  /* +128 source rows */                        \
      pV[i] += 128;     /* +128 s columns  */                        \
    }                                                                 \
  }

  // Q B-frags: lane holds Q[q0 + l32][k = ks*16 + hi*8 + i]
  short8 qf[4];
#pragma unroll
  for (int ks = 0; ks < 4; ++ks)
    qf[ks] = *(const short8*)(Qp + base + (size_t)(q0 + l32) * 1024 + ks * 16 + hi * 8);

  floatx16 of0 = {}, of1 = {};   // O[q][d] C-frags
  float rs = 0.f;                // per-lane partial rowsum

  const int swzb = (l32 & 15);
  const int krow = l32 * 256;    // byte base of LDS row l32 (row +32 = +8192)

  STAGE_ALL(0);
  __syncthreads();

#define QK_Q(SF, CUR, H, RH)                                                          \
  {                                                                                   \
    _Pragma("unroll") for (int ks = 0; ks < 4; ++ks) {                                \
      int kbyte = krow + (RH) * 8192 + ((((H) * 8 + 2 * ks + hi) ^ swzb) << 4);       \
      short8 kf = *(const short8*)((char*)Kl[CUR] + kbyte);                           \
      SF = MFMA32(kf, qf[ks], SF);                                                    \
    }                                                                                 \
  }

#define EXPPACK(SF, P0, P1)                                                           \
  {                                                                                   \
    _Pragma("unroll") for (int r = 0; r < 16; ++r) {                                  \
      SF[r] = __builtin_amdgcn_exp2f(SF[r]);                                          \
      rs += SF[r];                                                                    \
    }                                                                                 \
    uint32_t a0, a1, b0, b1;                                                          \
    CVTPK(SF[0], SF[1], a0); CVTPK(SF[2], SF[3], a1);                                 \
    CVTPK(SF[4], SF[5], b0); CVTPK(SF[6], SF[7], b1);                                 \
    SWAP32(a0, b0); SWAP32(a1, b1);                                                   \
    P0.u[0] = a0; P0.u[1] = a1; P0.u[2] = b0; P0.u[3] = b1;                           \
    CVTPK(SF[8], SF[9], a0); CVTPK(SF[10], SF[11], a1);                               \
    CVTPK(SF[12], SF[13], b0); CVTPK(SF[14], SF[15], b1);                             \
    SWAP32(a0, b0); SWAP32(a1, b1);                                                   \
    P1.u[0] = a0; P1.u[1] = a1; P1.u[2] = b0; P1.u[3] = b1;                           \
  }

#define PV_Q(P0, P1, CUR, H, RH)                                                      \
  {                                                                                   \
    int vb0 = krow + ((((H) * 8 + 2 * (2 * (RH)) + hi) ^ swzb) << 4);                 \
    int vb1 = krow + ((((H) * 8 + 2 * (2 * (RH) + 1) + hi) ^ swzb) << 4);             \
    short8 vf00 = *(const short8*)((char*)Vl[CUR] + vb0);                             \
    short8 vf01 = *(const short8*)((char*)Vl[CUR] + vb0 + 8192);                      \
    short8 vf10 = *(const short8*)((char*)Vl[CUR] + vb1);                             \
    short8 vf11 = *(const short8*)((char*)Vl[CUR] + vb1 + 8192);                      \
    of0 = MFMA32(P0.s, vf00, of0);                                                    \
    of1 = MFMA32(P0.s, vf01, of1);                                                    \
    of0 = MFMA32(P1.s, vf10, of0);                                                    \
    of1 = MFMA32(P1.s, vf11, of1);                                                    \
  }

#define STEP128(CUR, PF)                                                              \
  {                                                                                   \
    if (PF) STAGE_ALL(CUR ^ 1);                                                       \
    floatx16 sfA = {}, sfB = {};                                                      \
    QK_Q(sfA, CUR, 0, 0);                                                             \
    QK_Q(sfB, CUR, 0, 1);                                                             \
    {                                                                                 \
      PAu p0, p1;                                                                     \
      EXPPACK(sfA, p0, p1);                                                           \
      PV_Q(p0, p1, CUR, 0, 0);                                                        \
    }                                                                                 \
    sfA = (floatx16){};                                                               \
    QK_Q(sfA, CUR, 1, 0);                                                             \
    {                                                                                 \
      PAu p0, p1;                                                                     \
      EXPPACK(sfB, p0, p1);                                                           \
      PV_Q(p0, p1, CUR, 0, 1);                                                        \
    }                                                                                 \
    sfB = (floatx16){};                                                               \
    QK_Q(sfB, CUR, 1, 1);                                                             \
    {                                                                                 \
      PAu p0, p1;                                                                     \
      EXPPACK(sfA, p0, p1);                                                           \
      PV_Q(p0, p1, CUR, 1, 0);                                                        \
    }                                                                                 \
    {                                                                                 \
      PAu p0, p1;                                                                     \
      EXPPACK(sfB, p0, p1);                                                           \
      PV_Q(p0, p1, CUR, 1, 1);                                                        \
    }                                                                                 \
    __syncthreads();                                                                  \
  }

  for (int it = 0; it < 8; ++it) {   // 16 kv-tiles of 128, 2 per iteration
    STEP128(0, 1);
    STEP128(1, it < 7);
  }

  // --- epilogue: complete rowsums and normalize.
  rs += __shfl_xor(rs, 32);          // full rowsum for q = l32 (both hi halves)
#pragma unroll
  for (int r = 0; r < 16; ++r) {
    int qloc = (r & 3) + 8 * (r >> 2) + 4 * hi;       // q index of of-frag row r
    float rsq = __shfl(rs, qloc);                      // rowsum for that q
    float rinv = 1.0f / rsq;
    int qrow = q0 + qloc;
    AO[base + (size_t)qrow * 1024 + l32]      = f2bf(of0[r] * rinv);
    AO[base + (size_t)qrow * 1024 + 32 + l32] = f2bf(of1[r] * rinv);
  }
#undef STAGE_ALL
#undef QK_Q
#undef EXPPACK
#undef PV_Q
#undef STEP128
}

// ---------- launch ----------
extern "C" void kernel_launch(void* const* d_in, const int* in_sizes, int n_in,
                              void* d_out, int out_size, void* d_ws, size_t ws_size,
                              hipStream_t stream) {
  const float* q  = (const float*)d_in[0];
  const float* k  = (const float*)d_in[1];
  const float* v  = (const float*)d_in[2];
  const float* Wq = (const float*)d_in[3];
  const float* bq = (const float*)d_in[4];
  const float* Wk = (const float*)d_in[5];
  const float* bk = (const float*)d_in[6];
  const float* Wv = (const float*)d_in[7];
  const float* bv = (const float*)d_in[8];
  const float* Wo = (const float*)d_in[9];
  const float* bo = (const float*)d_in[10];

  const size_t MB = 1ull << 20;
  char* ws = (char*)d_ws;
  uint16_t* XQ  = (uint16_t*)(ws + 0 * MB);    // 16MB x3, contiguous (cvt strides)
  uint16_t* XK  = (uint16_t*)(ws + 16 * MB);
  uint16_t* XV  = (uint16_t*)(ws + 32 * MB);
  uint16_t* WQb = (uint16_t*)(ws + 48 * MB);   // 2MB x4, contiguous (cvt strides)
  uint16_t* WKb = (uint16_t*)(ws + 50 * MB);
  uint16_t* WVb = (uint16_t*)(ws + 52 * MB);
  uint16_t* WOb = (uint16_t*)(ws + 54 * MB);
  uint16_t* QP  = (uint16_t*)(ws + 56 * MB);
  uint16_t* KP  = (uint16_t*)(ws + 72 * MB);
  uint16_t* VT  = (uint16_t*)(ws + 88 * MB);   // V projected + transposed, 16MB
  uint16_t* AO  = XQ;   // alias: XQ dead after QKV projection

  const float qscale = 0.125f * 1.4426950408889634f;  // softmax scale * log2e -> exp2

  cvt7_k<<<dim3(2048, 1, 7), dim3(256), 0, stream>>>(q, k, v, Wq, Wk, Wv, Wo, XQ, WQb);

  gemm_qkv_k<<<dim3(8, 32, 3), dim3(512), 0, stream>>>(
      XQ, XK, XV, WQb, WKb, WVb, bq, bk, bv, QP, KP, VT, qscale);

  attn_k<<<dim3(8, 64), dim3(512), 0, stream>>>(QP, KP, VT, AO);

  gemm_o_k<<<dim3(8, 32), dim3(512), 0, stream>>>(AO, WOb, bo, (float*)d_out);
}

// Round 20
// 185.160 us; speedup vs baseline: 1.0533x; 1.0068x over previous
//
#include <hip/hip_runtime.h>
#include <hip/hip_bf16.h>
#include <stdint.h>

// ---------- types ----------
typedef __attribute__((ext_vector_type(8))) short short8;      // 8 bf16 (MFMA A/B frag)
typedef __attribute__((ext_vector_type(4))) float floatx4;     // 16x16 C/D frag
typedef __attribute__((ext_vector_type(16))) float floatx16;   // 32x32 C/D frag
typedef __attribute__((ext_vector_type(4))) uint16_t ushort4v;

#define MFMA16(a, b, c) __builtin_amdgcn_mfma_f32_16x16x32_bf16((a), (b), (c), 0, 0, 0)
#define MFMA32(a, b, c) __builtin_amdgcn_mfma_f32_32x32x16_bf16((a), (b), (c), 0, 0, 0)

// async global->LDS, 16B per lane; LDS dest is wave-uniform base + lane*16
#define GLOAD_LDS16(g, l)                                                          \
  __builtin_amdgcn_global_load_lds(                                                \
      (const __attribute__((address_space(1))) uint32_t*)(g),                      \
      (__attribute__((address_space(3))) uint32_t*)(l), 16, 0, 0)

// packed f32x2 -> bf16x2
#define CVTPK(lo_, hi_, out_) \
  asm("v_cvt_pk_bf16_f32 %0, %1, %2" : "=v"(out_) : "v"(lo_), "v"(hi_))
// exchange a's high 32 lanes with b's low 32 lanes
#define SWAP32(a_, b_) \
  asm("v_permlane32_swap_b32 %0, %1" : "+v"(a_), "+v"(b_))

#define WAITVM(N)                                          \
  {                                                        \
    asm volatile("s_waitcnt vmcnt(" #N ")" ::: "memory");  \
    __builtin_amdgcn_sched_barrier(0);                     \
  }
#define SBAR                                               \
  {                                                        \
    __builtin_amdgcn_s_barrier();                          \
    __builtin_amdgcn_sched_barrier(0);                     \
  }

// fp32 -> bf16 round-to-nearest-even
__device__ __forceinline__ uint16_t f2bf(float x) {
  union { float f; uint32_t u; } c; c.f = x;
  return (uint16_t)((c.u + 0x7FFFu + ((c.u >> 16) & 1u)) >> 16);
}

// ---------- fp32 -> bf16 convert, all 7 tensors in one launch (z = 0..6) ----------
__global__ void cvt7_k(const float* __restrict__ q, const float* __restrict__ k,
                       const float* __restrict__ v, const float* __restrict__ w0,
                       const float* __restrict__ w1, const float* __restrict__ w2,
                       const float* __restrict__ w3, uint16_t* __restrict__ dstBig,
                       uint16_t* __restrict__ dstW) {
  const int z = blockIdx.z;
  const float* src;
  uint16_t* d;
  int n4;
  if (z < 3) {
    src = z == 0 ? q : (z == 1 ? k : v);
    d = dstBig + (size_t)z * 8388608;   // 16MB stride
    n4 = 2097152;
  } else {
    const int i = z - 3;
    src = i == 0 ? w0 : (i == 1 ? w1 : (i == 2 ? w2 : w3));
    d = dstW + (size_t)i * 1048576;     // 2MB stride
    n4 = 262144;
  }
  int stride = gridDim.x * blockDim.x;
  for (int i = blockIdx.x * blockDim.x + threadIdx.x; i < n4; i += stride) {
    float4 vv = ((const float4*)src)[i];
    ushort4v o;
    o.x = f2bf(vv.x); o.y = f2bf(vv.y); o.z = f2bf(vv.z); o.w = f2bf(vv.w);
    ((ushort4v*)d)[i] = o;
  }
}

// ---------- GEMM: 256x128 tile, BK=64, 8 waves, 3-buffer counted-vmcnt pipeline ----
// LDS declared in the CALLER kernel (single allocation) and passed in.
// Per K-tile kt: stage kt+2 -> buf[(kt+2)%3] (6 gload_lds), compute buf[kt%3],
// s_waitcnt vmcnt(6) (kt+1's 6 loads are the oldest; fresh loads stay in flight),
// raw s_barrier (no vmcnt(0) drain).
// LDS half-unit (R6/R11 pattern): [64 r][16 slots x 16B]; slot q of row r holds
// q0 = q^(r&15): source row 64*(q0>>3)+r, kchunk q0&7. Conflict-free (counters: 0).
// NOTE (R17/R18 post-mortem): per-wave 128x64 / 256x256-tile variants spill —
// this toolchain pins 512-thread kernels at 128 VGPR regardless of launch_bounds
// or amdgpu_waves_per_eu hints. Keep per-wave 64x64 (acc = 64 VGPR).
// MODE: 0 = f32 out, 1 = bf16 out, 2 = bf16 V-transposed out.
template <int MODE>
__device__ __forceinline__ void gemm256_body(uint16_t* __restrict__ As,   // LDS, 3*16384
                                             uint16_t* __restrict__ Bs,   // LDS, 3*8192
                                             const uint16_t* __restrict__ A,
                                             const uint16_t* __restrict__ W,
                                             const float* __restrict__ bias,
                                             void* __restrict__ Cout, float scale,
                                             int brow, int bcol) {
  constexpr int N = 1024, K = 1024;
  const int t = threadIdx.x;
  const int l = t & 63, w = t >> 6;       // 8 waves
  const int l16 = l & 15, lhi = (l >> 4) & 3;
  const int wm = w >> 1, wn = w & 1;      // 4 M-waves x 2 N-waves; per-wave C 64x64

  // staging source pointers (advance +64 per K-tile)
  const uint16_t* pA[4];
  const uint16_t* pB[2];
#pragma unroll
  for (int i = 0; i < 4; ++i) {
    int cw = (i * 512 + t) & 1023;
    int r = cw >> 4, q = cw & 15;
    int q0 = q ^ (r & 15);
    pA[i] = A + (size_t)(brow + (i >> 1) * 128 + 64 * (q0 >> 3) + r) * K + (q0 & 7) * 8;
  }
#pragma unroll
  for (int i = 0; i < 2; ++i) {
    int c = i * 512 + t;
    int r = c >> 4, q = c & 15;
    int q0 = q ^ (r & 15);
    pB[i] = W + (size_t)(bcol + 64 * (q0 >> 3) + r) * K + (q0 & 7) * 8;
  }

#define G_STAGE(BUF)                                                      \
  {                                                                       \
    _Pragma("unroll") for (int i = 0; i < 4; ++i) {                       \
      GLOAD_LDS16(pA[i], As + (BUF) * 16384 + i * 4096 + w * 512);        \
      pA[i] += 64;                                                        \
    }                                                                     \
    _Pragma("unroll") for (int i = 0; i < 2; ++i) {                       \
      GLOAD_LDS16(pB[i], Bs + (BUF) * 8192 + i * 4096 + w * 512);         \
      pB[i] += 64;                                                        \
    }                                                                     \
  }

  floatx4 acc[4][4] = {};

  // A-frag (m,ks): byte = (wm>>1)*16384 + (m*16+l16)*256 + (((wm&1)*8+ks*4+lhi)^l16)*16
  // B-frag (n,ks): byte = (n*16+l16)*256 + ((wn*8+ks*4+lhi)^l16)*16
#define G_COMPUTE(BUF)                                                               \
  {                                                                                  \
    short8 a[4][2], b[4][2];                                                         \
    _Pragma("unroll") for (int m = 0; m < 4; ++m)                                    \
      _Pragma("unroll") for (int ks = 0; ks < 2; ++ks)                               \
        a[m][ks] = *(const short8*)((const char*)(As + (BUF) * 16384) +              \
            (wm >> 1) * 16384 +                                                      \
            (m * 16 + l16) * 256 + ((((wm & 1) * 8 + ks * 4 + lhi) ^ l16) << 4));    \
    _Pragma("unroll") for (int n = 0; n < 4; ++n)                                    \
      _Pragma("unroll") for (int ks = 0; ks < 2; ++ks)                               \
        b[n][ks] = *(const short8*)((const char*)(Bs + (BUF) * 8192) +               \
            (n * 16 + l16) * 256 + (((wn * 8 + ks * 4 + lhi) ^ l16) << 4));          \
    __builtin_amdgcn_s_setprio(1);                                                   \
    _Pragma("unroll") for (int ks = 0; ks < 2; ++ks)                                 \
      _Pragma("unroll") for (int m = 0; m < 4; ++m)                                  \
        _Pragma("unroll") for (int n = 0; n < 4; ++n)                                \
          acc[m][n] = MFMA16(a[m][ks], b[n][ks], acc[m][n]);                         \
    __builtin_amdgcn_s_setprio(0);                                                   \
  }

#define G_STEP(RD, ST)   \
  {                      \
    G_STAGE(ST);         \
    G_COMPUTE(RD);       \
    WAITVM(6);           \
    SBAR;                \
  }

  // prologue: stage kt=0,1; wait kt0 resident (6 of 12 oldest)
  G_STAGE(0);
  G_STAGE(1);
  WAITVM(6);
  SBAR;

  // kt = 0..11 (stage kt+2 = 2..13)
#pragma unroll 1
  for (int g = 0; g < 4; ++g) {
    G_STEP(0, 2);
    G_STEP(1, 0);
    G_STEP(2, 1);
  }
  G_STEP(0, 2);   // kt=12, stage 14
  G_STEP(1, 0);   // kt=13, stage 15
  // kt=14: no more staging; drain kt15's loads
  G_COMPUTE(2);
  WAITVM(0);
  SBAR;
  // kt=15
  G_COMPUTE(0);

  // ---- epilogue ----
#pragma unroll
  for (int n = 0; n < 4; ++n) {
    int col = bcol + wn * 64 + n * 16 + l16;
    float bv = bias[col];
    if (MODE == 2) {
      int h = col >> 6, d = col & 63;
#pragma unroll
      for (int m = 0; m < 4; ++m) {
        int row = brow + wm * 64 + m * 16 + lhi * 4;   // j=0 row
        int b_ = row >> 11, s = row & 2047;
        union { uint16_t u[4]; ushort4v v; } pk4;
#pragma unroll
        for (int j = 0; j < 4; ++j) pk4.u[j] = f2bf(acc[m][n][j] + bv);
        *(ushort4v*)((uint16_t*)Cout + (size_t)(b_ * 16 + h) * 131072 + (size_t)d * 2048 + s) = pk4.v;
      }
    } else {
#pragma unroll
      for (int m = 0; m < 4; ++m) {
#pragma unroll
        for (int j = 0; j < 4; ++j) {
          int row = brow + wm * 64 + m * 16 + lhi * 4 + j;
          float v = (acc[m][n][j] + bv) * scale;
          if (MODE == 1)
            ((uint16_t*)Cout)[(size_t)row * N + col] = f2bf(v);
          else
            ((float*)Cout)[(size_t)row * N + col] = v;
        }
      }
    }
  }
#undef G_STAGE
#undef G_COMPUTE
#undef G_STEP
}

// fused Q/K/V projections: 768 blocks (8x, 32y, 3z), XCD-chunked; V pre-transposed.
__global__ __launch_bounds__(512, 1)
void gemm_qkv_k(const uint16_t* __restrict__ XQ, const uint16_t* __restrict__ XK,
                const uint16_t* __restrict__ XV, const uint16_t* __restrict__ WQ,
                const uint16_t* __restrict__ WK, const uint16_t* __restrict__ WV,
                const float* __restrict__ bq, const float* __restrict__ bk,
                const float* __restrict__ bv, uint16_t* __restrict__ QP,
                uint16_t* __restrict__ KP, uint16_t* __restrict__ VT, float qscale) {
  __shared__ uint16_t As[3 * 16384];   // 96KB
  __shared__ uint16_t Bs[3 * 8192];    // 48KB
  const int f = (blockIdx.z * 32 + blockIdx.y) * 8 + blockIdx.x;
  const int virt = (f & 7) * 96 + (f >> 3);     // 768 = 8*96, bijective
  const int vz = virt >> 8;
  const int rem = virt & 255;
  const int vy = rem >> 3, vx = rem & 7;

  if (vz == 0)      gemm256_body<1>(As, Bs, XQ, WQ, bq, QP, qscale, vy * 256, vx * 128);
  else if (vz == 1) gemm256_body<1>(As, Bs, XK, WK, bk, KP, 1.0f,  vy * 256, vx * 128);
  else              gemm256_body<2>(As, Bs, XV, WV, bv, VT, 1.0f,  vy * 256, vx * 128);
}

// output projection: 256 blocks (8x, 32y), XCD-chunked.
__global__ __launch_bounds__(512, 1)
void gemm_o_k(const uint16_t* __restrict__ A, const uint16_t* __restrict__ W,
              const float* __restrict__ bias, float* __restrict__ Cout) {
  __shared__ uint16_t As[3 * 16384];
  __shared__ uint16_t Bs[3 * 8192];
  const int f = blockIdx.y * 8 + blockIdx.x;
  const int virt = (f & 7) * 32 + (f >> 3);
  const int vy = virt >> 3, vx = virt & 7;
  gemm256_body<0>(As, Bs, A, W, bias, Cout, 1.0f, vy * 256, vx * 128);
}

// ---------- flash attention: quarter-pipelined (QK_next ∥ exp/pack_cur) ----------
__global__ __launch_bounds__(512, 2)
void attn_k(const uint16_t* __restrict__ Qp, const uint16_t* __restrict__ Kp,
            const uint16_t* __restrict__ Vt, uint16_t* __restrict__ AO) {
  __shared__ uint16_t Kl[2][64 * 128];   // 16KB per buffer
  __shared__ uint16_t Vl[2][64 * 128];   // 16KB per buffer

  const int t = threadIdx.x;
  const int l = t & 63, w = t >> 6;       // w = 0..7
  const int l32 = l & 31, hi = l >> 5;

  // XCD-chunked swizzle: 512 blocks, 64 per XCD -> 8 contiguous bh groups each.
  const int f = blockIdx.y * 8 + blockIdx.x;
  const int virt = (f & 7) * 64 + (f >> 3);
  const int vx = virt & 7;     // q-block (256 q each)
  const int vy = virt >> 3;    // bh

  const int q0 = vx * 256 + w * 32;
  const size_t base = (size_t)(vy >> 4) * 2048 * 1024 + (size_t)(vy & 15) * 64;
  const size_t vbg = (size_t)vy * 131072;  // (b*16+h)*64*2048

  union PAu { uint32_t u[4]; short8 s; };

  // staging: 1024 chunks per matrix per tile; 512 threads -> 2 issues each.
  const uint16_t* pK[2];
  const uint16_t* pV[2];
#pragma unroll
  for (int i = 0; i < 2; ++i) {
    int c = i * 512 + t;
    int r = c >> 4, qs = c & 15;
    int q0c = qs ^ (r & 15);
    pK[i] = Kp + base + (size_t)(64 * (q0c >> 3) + r) * 1024 + (q0c & 7) * 8;
    pV[i] = Vt + vbg + (size_t)r * 2048 + q0c * 8;
  }

#define STAGE_ALL(NB)                                                 \
  {                                                                   \
    _Pragma("unroll") for (int i = 0; i < 2; ++i) {                   \
      GLOAD_LDS16(pK[i], &Kl[NB][(size_t)(i * 512 + w * 64) * 8]);    \
      GLOAD_LDS16(pV[i], &Vl[NB][(size_t)(i * 512 + w * 64) * 8]);    \
      pK[i] += 131072;  /* +128 source rows */                        \
      pV[i] += 128;     /* +128 s columns  */                        \
    }                                                                 \
  }

  // Q B-frags: lane holds Q[q0 + l32][k = ks*16 + hi*8 + i]
  short8 qf[4];
#pragma unroll
  for (int ks = 0; ks < 4; ++ks)
    qf[ks] = *(const short8*)(Qp + base + (size_t)(q0 + l32) * 1024 + ks * 16 + hi * 8);

  floatx16 of0 = {}, of1 = {};   // O[q][d] C-frags
  float rs = 0.f;                // per-lane partial rowsum

  const int swzb = (l32 & 15);
  const int krow = l32 * 256;    // byte base of LDS row l32 (row +32 = +8192)

  STAGE_ALL(0);
  __syncthreads();

#define QK_Q(SF, CUR, H, RH)                                                          \
  {                                                                                   \
    _Pragma("unroll") for (int ks = 0; ks < 4; ++ks) {                                \
      int kbyte = krow + (RH) * 8192 + ((((H) * 8 + 2 * ks + hi) ^ swzb) << 4);       \
      short8 kf = *(const short8*)((char*)Kl[CUR] + kbyte);                           \
      SF = MFMA32(kf, qf[ks], SF);                                                    \
    }                                                                                 \
  }

#define EXPPACK(SF, P0, P1)                                                           \
  {                                                                                   \
    _Pragma("unroll") for (int r = 0; r < 16; ++r) {                                  \
      SF[r] = __builtin_amdgcn_exp2f(SF[r]);                                          \
      rs += SF[r];                                                                    \
    }                                                                                 \
    uint32_t a0, a1, b0, b1;                                                          \
    CVTPK(SF[0], SF[1], a0); CVTPK(SF[2], SF[3], a1);                                 \
    CVTPK(SF[4], SF[5], b0); CVTPK(SF[6], SF[7], b1);                                 \
    SWAP32(a0, b0); SWAP32(a1, b1);                                                   \
    P0.u[0] = a0; P0.u[1] = a1; P0.u[2] = b0; P0.u[3] = b1;                           \
    CVTPK(SF[8], SF[9], a0); CVTPK(SF[10], SF[11], a1);                               \
    CVTPK(SF[12], SF[13], b0); CVTPK(SF[14], SF[15], b1);                             \
    SWAP32(a0, b0); SWAP32(a1, b1);                                                   \
    P1.u[0] = a0; P1.u[1] = a1; P1.u[2] = b0; P1.u[3] = b1;                           \
  }

#define PV_Q(P0, P1, CUR, H, RH)                                                      \
  {                                                                                   \
    int vb0 = krow + ((((H) * 8 + 2 * (2 * (RH)) + hi) ^ swzb) << 4);                 \
    int vb1 = krow + ((((H) * 8 + 2 * (2 * (RH) + 1) + hi) ^ swzb) << 4);             \
    short8 vf00 = *(const short8*)((char*)Vl[CUR] + vb0);                             \
    short8 vf01 = *(const short8*)((char*)Vl[CUR] + vb0 + 8192);                      \
    short8 vf10 = *(const short8*)((char*)Vl[CUR] + vb1);                             \
    short8 vf11 = *(const short8*)((char*)Vl[CUR] + vb1 + 8192);                      \
    of0 = MFMA32(P0.s, vf00, of0);                                                    \
    of1 = MFMA32(P0.s, vf01, of1);                                                    \
    of0 = MFMA32(P1.s, vf10, of0);                                                    \
    of1 = MFMA32(P1.s, vf11, of1);                                                    \
  }

#define STEP128(CUR, PF)                                                              \
  {                                                                                   \
    if (PF) STAGE_ALL(CUR ^ 1);                                                       \
    floatx16 sfA = {}, sfB = {};                                                      \
    QK_Q(sfA, CUR, 0, 0);                                                             \
    QK_Q(sfB, CUR, 0, 1);                                                             \
    {                                                                                 \
      PAu p0, p1;                                                                     \
      EXPPACK(sfA, p0, p1);                                                           \
      PV_Q(p0, p1, CUR, 0, 0);                                                        \
    }                                                                                 \
    sfA = (floatx16){};                                                               \
    QK_Q(sfA, CUR, 1, 0);                                                             \
    {                                                                                 \
      PAu p0, p1;                                                                     \
      EXPPACK(sfB, p0, p1);                                                           \
      PV_Q(p0, p1, CUR, 0, 1);                                                        \
    }                                                                                 \
    sfB = (floatx16){};                                                               \
    QK_Q(sfB, CUR, 1, 1);                                                             \
    {                                                                                 \
      PAu p0, p1;                                                                     \
      EXPPACK(sfA, p0, p1);                                                           \
      PV_Q(p0, p1, CUR, 1, 0);                                                        \
    }                                                                                 \
    {                                                                                 \
      PAu p0, p1;                                                                     \
      EXPPACK(sfB, p0, p1);                                                           \
      PV_Q(p0, p1, CUR, 1, 1);                                                        \
    }                                                                                 \
    __syncthreads();                                                                  \
  }

  for (int it = 0; it < 8; ++it) {   // 16 kv-tiles of 128, 2 per iteration
    STEP128(0, 1);
    STEP128(1, it < 7);
  }

  // --- epilogue: complete rowsums and normalize.
  rs += __shfl_xor(rs, 32);          // full rowsum for q = l32 (both hi halves)
#pragma unroll
  for (int r = 0; r < 16; ++r) {
    int qloc = (r & 3) + 8 * (r >> 2) + 4 * hi;       // q index of of-frag row r
    float rsq = __shfl(rs, qloc);                      // rowsum for that q
    float rinv = 1.0f / rsq;
    int qrow = q0 + qloc;
    AO[base + (size_t)qrow * 1024 + l32]      = f2bf(of0[r] * rinv);
    AO[base + (size_t)qrow * 1024 + 32 + l32] = f2bf(of1[r] * rinv);
  }
#undef STAGE_ALL
#undef QK_Q
#undef EXPPACK
#undef PV_Q
#undef STEP128
}

// ---------- launch ----------
extern "C" void kernel_launch(void* const* d_in, const int* in_sizes, int n_in,
                              void* d_out, int out_size, void* d_ws, size_t ws_size,
                              hipStream_t stream) {
  const float* q  = (const float*)d_in[0];
  const float* k  = (const float*)d_in[1];
  const float* v  = (const float*)d_in[2];
  const float* Wq = (const float*)d_in[3];
  const float* bq = (const float*)d_in[4];
  const float* Wk = (const float*)d_in[5];
  const float* bk = (const float*)d_in[6];
  const float* Wv = (const float*)d_in[7];
  const float* bv = (const float*)d_in[8];
  const float* Wo = (const float*)d_in[9];
  const float* bo = (const float*)d_in[10];

  const size_t MB = 1ull << 20;
  char* ws = (char*)d_ws;
  uint16_t* XQ  = (uint16_t*)(ws + 0 * MB);    // 16MB x3, contiguous (cvt strides)
  uint16_t* XK  = (uint16_t*)(ws + 16 * MB);
  uint16_t* XV  = (uint16_t*)(ws + 32 * MB);
  uint16_t* WQb = (uint16_t*)(ws + 48 * MB);   // 2MB x4, contiguous (cvt strides)
  uint16_t* WKb = (uint16_t*)(ws + 50 * MB);
  uint16_t* WVb = (uint16_t*)(ws + 52 * MB);
  uint16_t* WOb = (uint16_t*)(ws + 54 * MB);
  uint16_t* QP  = (uint16_t*)(ws + 56 * MB);
  uint16_t* KP  = (uint16_t*)(ws + 72 * MB);
  uint16_t* VT  = (uint16_t*)(ws + 88 * MB);   // V projected + transposed, 16MB
  uint16_t* AO  = XQ;   // alias: XQ dead after QKV projection

  const float qscale = 0.125f * 1.4426950408889634f;  // softmax scale * log2e -> exp2

  cvt7_k<<<dim3(2048, 1, 7), dim3(256), 0, stream>>>(q, k, v, Wq, Wk, Wv, Wo, XQ, WQb);

  gemm_qkv_k<<<dim3(8, 32, 3), dim3(512), 0, stream>>>(
      XQ, XK, XV, WQb, WKb, WVb, bq, bk, bv, QP, KP, VT, qscale);

  attn_k<<<dim3(8, 64), dim3(512), 0, stream>>>(QP, KP, VT, AO);

  gemm_o_k<<<dim3(8, 32), dim3(512), 0, stream>>>(AO, WOb, bo, (float*)d_out);
}